// Round 1
// baseline (2164.655 us; speedup 1.0000x reference)
//
#include <hip/hip_runtime.h>

#define N_NODES 50000
#define N_EDGES 800000
#define D 128
#define R_REL 4
#define L_LAYERS 3
#define M_SEG (N_NODES * R_REL)
#define NCOLS 384
#define BN_EPS 1e-5f

// ---------------- weight packing: Wp[(l*5+p)][k][j], p=0 self(Wsk|Wfsk), p=1..4 rel(Wr|Wf)
__global__ void pack_w(const float* __restrict__ Wsk, const float* __restrict__ Wfsk,
                       const float* __restrict__ Wr, const float* __restrict__ Wf,
                       float* __restrict__ Wp) {
    int idx = blockIdx.x * 256 + threadIdx.x;
    if (idx >= L_LAYERS * 5 * D * NCOLS) return;
    int j = idx % NCOLS;
    int rem = idx / NCOLS;
    int k = rem % D;
    int lp = rem / D;
    int l = lp / 5, p = lp % 5;
    float v;
    if (p == 0) {
        v = (j < D) ? Wsk[(l * D + k) * D + j] : Wfsk[(l * D + k) * 2 * D + (j - D)];
    } else {
        int r = p - 1;
        v = (j < D) ? Wr[((l * R_REL + r) * D + k) * D + j]
                    : Wf[((l * R_REL + r) * D + k) * 2 * D + (j - D)];
    }
    Wp[idx] = v;
}

// ---------------- CSR build over segments seg = dst*R + etype
__global__ void hist_k(const int* __restrict__ dst, const int* __restrict__ et, int* __restrict__ cnt) {
    int e = blockIdx.x * 256 + threadIdx.x;
    if (e >= N_EDGES) return;
    atomicAdd(&cnt[dst[e] * R_REL + et[e]], 1);
}

__global__ void scan_a(const int* __restrict__ cnt, int* __restrict__ bsum) {
    __shared__ int sm[256];
    int t = threadIdx.x;
    int idx = blockIdx.x * 256 + t;
    sm[t] = (idx < M_SEG) ? cnt[idx] : 0;
    __syncthreads();
    for (int s = 128; s > 0; s >>= 1) {
        if (t < s) sm[t] += sm[t + s];
        __syncthreads();
    }
    if (t == 0) bsum[blockIdx.x] = sm[0];
}

#define NB_SCAN 782  // ceil(200000/256)
__global__ void scan_b(const int* __restrict__ bsum, int* __restrict__ bsumex, int* __restrict__ offs) {
    __shared__ int sm[1024];
    int t = threadIdx.x;
    int v = (t < NB_SCAN) ? bsum[t] : 0;
    sm[t] = v;
    __syncthreads();
    for (int d = 1; d < 1024; d <<= 1) {
        int add = (t >= d) ? sm[t - d] : 0;
        __syncthreads();
        sm[t] += add;
        __syncthreads();
    }
    if (t < NB_SCAN) bsumex[t] = sm[t] - v;
    if (t == NB_SCAN - 1) offs[M_SEG] = sm[t];
}

__global__ void scan_c(const int* __restrict__ cnt, const int* __restrict__ bsumex, int* __restrict__ offs) {
    __shared__ int sm[256];
    int t = threadIdx.x;
    int idx = blockIdx.x * 256 + t;
    int v = (idx < M_SEG) ? cnt[idx] : 0;
    sm[t] = v;
    __syncthreads();
    for (int d = 1; d < 256; d <<= 1) {
        int add = (t >= d) ? sm[t - d] : 0;
        __syncthreads();
        sm[t] += add;
        __syncthreads();
    }
    if (idx < M_SEG) offs[idx] = bsumex[blockIdx.x] + sm[t] - v;
}

__global__ void scatter_k(const int* __restrict__ src, const int* __restrict__ dst,
                          const int* __restrict__ et, const int* __restrict__ offs,
                          int* __restrict__ tmp, int* __restrict__ esrc) {
    int e = blockIdx.x * 256 + threadIdx.x;
    if (e >= N_EDGES) return;
    int seg = dst[e] * R_REL + et[e];
    int pos = offs[seg] + atomicAdd(&tmp[seg], 1);
    esrc[pos] = src[e];
}

// ---------------- fp32 GEMM: C[N,384] = A[N,128] @ W[128,384]
// BM=64, BN=64, BK=64 x2, 256 threads, 4x4 micro-tile
__global__ __launch_bounds__(256) void gemm384(const float* __restrict__ A, const float* __restrict__ W,
                                               float* __restrict__ C) {
    __shared__ float As[64 * 68];  // [k][row], pad 68
    __shared__ float Bs[64 * 64];  // [k][col]
    int t = threadIdx.x;
    int m0 = blockIdx.x * 64;
    int n0 = blockIdx.y * 64;
    int tx = t & 15, ty = t >> 4;
    float acc[4][4] = {};
    for (int kt = 0; kt < 2; ++kt) {
#pragma unroll
        for (int i = 0; i < 4; ++i) {
            int f = t + 256 * i;
            int row = f >> 4, k4 = f & 15;
            float4 v = make_float4(0.f, 0.f, 0.f, 0.f);
            int gr = m0 + row;
            if (gr < N_NODES) v = *reinterpret_cast<const float4*>(&A[gr * D + kt * 64 + k4 * 4]);
            As[(k4 * 4 + 0) * 68 + row] = v.x;
            As[(k4 * 4 + 1) * 68 + row] = v.y;
            As[(k4 * 4 + 2) * 68 + row] = v.z;
            As[(k4 * 4 + 3) * 68 + row] = v.w;
        }
#pragma unroll
        for (int i = 0; i < 4; ++i) {
            int f = t + 256 * i;
            int row = f >> 4, c4 = f & 15;
            float4 v = *reinterpret_cast<const float4*>(&W[(kt * 64 + row) * NCOLS + n0 + c4 * 4]);
            *reinterpret_cast<float4*>(&Bs[row * 64 + c4 * 4]) = v;
        }
        __syncthreads();
#pragma unroll 4
        for (int k = 0; k < 64; ++k) {
            float4 a = *reinterpret_cast<const float4*>(&As[k * 68 + ty * 4]);
            float4 b = *reinterpret_cast<const float4*>(&Bs[k * 64 + tx * 4]);
            acc[0][0] += a.x * b.x; acc[0][1] += a.x * b.y; acc[0][2] += a.x * b.z; acc[0][3] += a.x * b.w;
            acc[1][0] += a.y * b.x; acc[1][1] += a.y * b.y; acc[1][2] += a.y * b.z; acc[1][3] += a.y * b.w;
            acc[2][0] += a.z * b.x; acc[2][1] += a.z * b.y; acc[2][2] += a.z * b.z; acc[2][3] += a.z * b.w;
            acc[3][0] += a.w * b.x; acc[3][1] += a.w * b.y; acc[3][2] += a.w * b.z; acc[3][3] += a.w * b.w;
        }
        __syncthreads();
    }
#pragma unroll
    for (int i = 0; i < 4; ++i) {
        int gr = m0 + ty * 4 + i;
        if (gr < N_NODES) {
            float4 o = make_float4(acc[i][0], acc[i][1], acc[i][2], acc[i][3]);
            *reinterpret_cast<float4*>(&C[(size_t)gr * NCOLS + n0 + tx * 4]) = o;
        }
    }
}

// ---------------- self path: acc = relu(gamma_s * xsk + beta_s); buf cols: [0:128)=xsk,[128:256)=beta,[256:384)=gamma
__global__ void film_self(const float* __restrict__ buf, float* __restrict__ acc) {
    int idx = blockIdx.x * 256 + threadIdx.x;
    if (idx >= N_NODES * D) return;
    int n = idx >> 7, c = idx & 127;
    const float* row = buf + (size_t)n * NCOLS;
    float v = row[256 + c] * row[c] + row[128 + c];
    acc[idx] = fmaxf(v, 0.f);
}

// ---------------- per-relation aggregation: acc[n] += mean_e relu(gamma[n]*xr[src_e] + beta[n])
__global__ __launch_bounds__(128) void agg_rel(const float* __restrict__ buf, const int* __restrict__ offs,
                                               const int* __restrict__ esrc, float* __restrict__ acc, int r) {
    int n = blockIdx.x;
    int c = threadIdx.x;
    int seg = n * R_REL + r;
    int beg = offs[seg], end = offs[seg + 1];
    if (beg >= end) return;
    const float* row = buf + (size_t)n * NCOLS;
    float gamma = row[256 + c], beta = row[128 + c];
    float s = 0.f;
    for (int i = beg; i < end; ++i) {
        int src = esrc[i];
        s += fmaxf(gamma * buf[(size_t)src * NCOLS + c] + beta, 0.f);
    }
    acc[n * D + c] += s / (float)(end - beg);
}

// ---------------- batchnorm (training stats, biased var)
__global__ __launch_bounds__(128) void bn_stats(const float* __restrict__ acc, float* __restrict__ sums) {
    int c = threadIdx.x;
    int b = blockIdx.x;
    int chunk = (N_NODES + gridDim.x - 1) / gridDim.x;
    int n0 = b * chunk, n1 = min(n0 + chunk, N_NODES);
    float s = 0.f, s2 = 0.f;
    for (int n = n0; n < n1; ++n) {
        float v = acc[n * D + c];
        s += v;
        s2 += v * v;
    }
    atomicAdd(&sums[c], s);
    atomicAdd(&sums[128 + c], s2);
}

__global__ void bn_apply(const float* __restrict__ acc, const float* __restrict__ sums,
                         const float* __restrict__ w, const float* __restrict__ b, float* __restrict__ h) {
    int idx = blockIdx.x * 256 + threadIdx.x;
    if (idx >= N_NODES * D) return;
    int c = idx & 127;
    const float invn = 1.f / (float)N_NODES;
    float mu = sums[c] * invn;
    float var = sums[128 + c] * invn - mu * mu;
    float rs = rsqrtf(var + BN_EPS);
    h[idx] = (acc[idx] - mu) * rs * w[c] + b[c];
}

// ---------------- head: out = leaky_relu(h@W1+b1, 0.2) @ W2 + b2
__global__ __launch_bounds__(128) void head_k(const float* __restrict__ h, const float* __restrict__ w1,
                                              const float* __restrict__ b1, const float* __restrict__ w2,
                                              const float* __restrict__ b2, float* __restrict__ out) {
    __shared__ float hrow[128];
    __shared__ float part[128];
    __shared__ float mid[32];
    int n = blockIdx.x, t = threadIdx.x;
    hrow[t] = h[n * D + t];
    __syncthreads();
    int m = t & 31, q = t >> 5;
    float p = 0.f;
#pragma unroll 8
    for (int k = q * 32; k < q * 32 + 32; ++k) p += hrow[k] * w1[k * 32 + m];
    part[t] = p;
    __syncthreads();
    if (t < 32) {
        float v = part[t] + part[t + 32] + part[t + 64] + part[t + 96] + b1[t];
        mid[t] = v > 0.f ? v : 0.2f * v;
    }
    __syncthreads();
    if (t < 40) {
        float o = b2[t];
#pragma unroll 8
        for (int mm = 0; mm < 32; ++mm) o += mid[mm] * w2[mm * 40 + t];
        out[n * 40 + t] = o;
    }
}

extern "C" void kernel_launch(void* const* d_in, const int* in_sizes, int n_in,
                              void* d_out, int out_size, void* d_ws, size_t ws_size,
                              hipStream_t stream) {
    const float* x    = (const float*)d_in[0];
    const int*   ei   = (const int*)d_in[1];
    const int*   et   = (const int*)d_in[2];
    const float* Wsk  = (const float*)d_in[3];
    const float* Wfsk = (const float*)d_in[4];
    const float* Wr   = (const float*)d_in[5];
    const float* Wf   = (const float*)d_in[6];
    const float* bnw  = (const float*)d_in[7];
    const float* bnb  = (const float*)d_in[8];
    const float* w1   = (const float*)d_in[9];
    const float* b1   = (const float*)d_in[10];
    const float* w2   = (const float*)d_in[11];
    const float* b2   = (const float*)d_in[12];
    const int* src = ei;
    const int* dst = ei + N_EDGES;

    char* ws = (char*)d_ws;
    size_t off = 0;
    auto alloc = [&](size_t bytes) -> void* {
        void* p = ws + off;
        off += (bytes + 255) & ~(size_t)255;
        return p;
    };
    float* Wp     = (float*)alloc((size_t)L_LAYERS * 5 * D * NCOLS * 4);
    float* buf    = (float*)alloc((size_t)N_NODES * NCOLS * 4);
    float* acc    = (float*)alloc((size_t)N_NODES * D * 4);
    float* hbuf   = (float*)alloc((size_t)N_NODES * D * 4);
    int*   cnt    = (int*)alloc((size_t)M_SEG * 4);
    int*   offs   = (int*)alloc((size_t)(M_SEG + 1) * 4);
    int*   tmp    = (int*)alloc((size_t)M_SEG * 4);
    int*   esrc   = (int*)alloc((size_t)N_EDGES * 4);
    int*   bsum   = (int*)alloc(1024 * 4);
    int*   bsumex = (int*)alloc(1024 * 4);
    float* bns    = (float*)alloc(256 * 4);

    hipMemsetAsync(cnt, 0, (size_t)M_SEG * 4, stream);
    hipMemsetAsync(tmp, 0, (size_t)M_SEG * 4, stream);

    pack_w<<<(L_LAYERS * 5 * D * NCOLS + 255) / 256, 256, 0, stream>>>(Wsk, Wfsk, Wr, Wf, Wp);
    hist_k<<<(N_EDGES + 255) / 256, 256, 0, stream>>>(dst, et, cnt);
    scan_a<<<NB_SCAN, 256, 0, stream>>>(cnt, bsum);
    scan_b<<<1, 1024, 0, stream>>>(bsum, bsumex, offs);
    scan_c<<<NB_SCAN, 256, 0, stream>>>(cnt, bsumex, offs);
    scatter_k<<<(N_EDGES + 255) / 256, 256, 0, stream>>>(src, dst, et, offs, tmp, esrc);

    const int nbm = (N_NODES + 63) / 64;  // 782
    const float* hin = x;
    for (int l = 0; l < L_LAYERS; ++l) {
        gemm384<<<dim3(nbm, 6), 256, 0, stream>>>(hin, Wp + (size_t)(l * 5) * D * NCOLS, buf);
        film_self<<<(N_NODES * D + 255) / 256, 256, 0, stream>>>(buf, acc);
        for (int r = 0; r < R_REL; ++r) {
            gemm384<<<dim3(nbm, 6), 256, 0, stream>>>(hin, Wp + (size_t)(l * 5 + 1 + r) * D * NCOLS, buf);
            agg_rel<<<N_NODES, 128, 0, stream>>>(buf, offs, esrc, acc, r);
        }
        hipMemsetAsync(bns, 0, 256 * 4, stream);
        bn_stats<<<128, 128, 0, stream>>>(acc, bns);
        bn_apply<<<(N_NODES * D + 255) / 256, 256, 0, stream>>>(acc, bns, bnw + l * D, bnb + l * D, hbuf);
        hin = hbuf;
    }
    head_k<<<N_NODES, 128, 0, stream>>>(hbuf, w1, b1, w2, b2, (float*)d_out);
}

// Round 2
// 1157.801 us; speedup vs baseline: 1.8696x; 1.8696x over previous
//
#include <hip/hip_runtime.h>
#include <hip/hip_bf16.h>

#define N_NODES 50000
#define N_EDGES 800000
#define D 128
#define R_REL 4
#define L_LAYERS 3
#define M_SEG (N_NODES * R_REL)
#define NCOLS 384
#define BN_EPS 1e-5f

typedef __attribute__((ext_vector_type(8))) short short8v;
typedef __attribute__((ext_vector_type(4))) float f32x4;

static __device__ __forceinline__ unsigned short f2b(float f) {
    union { float f; unsigned int u; } a; a.f = f;
    unsigned int u = a.u;
    unsigned int r = (u + 0x7FFFu + ((u >> 16) & 1u)) >> 16;
    return (unsigned short)r;
}

// ---------------- weight packing: Wpb[(l*5+p)][j=0..383][k=0..127] bf16 (transposed so B-tile rows = out cols)
__global__ void pack_w(const float* __restrict__ Wsk, const float* __restrict__ Wfsk,
                       const float* __restrict__ Wr, const float* __restrict__ Wf,
                       unsigned short* __restrict__ Wpb) {
    int idx = blockIdx.x * 256 + threadIdx.x;
    if (idx >= L_LAYERS * 5 * NCOLS * D) return;
    int k = idx & 127;
    int rem = idx >> 7;
    int j = rem % NCOLS;
    int lp = rem / NCOLS;
    int l = lp / 5, p = lp % 5;
    float v;
    if (p == 0) {
        v = (j < D) ? Wsk[(l * D + k) * D + j] : Wfsk[(l * D + k) * 2 * D + (j - D)];
    } else {
        int r = p - 1;
        v = (j < D) ? Wr[((l * R_REL + r) * D + k) * D + j]
                    : Wf[((l * R_REL + r) * D + k) * 2 * D + (j - D)];
    }
    Wpb[idx] = f2b(v);
}

// ---------------- x -> bf16
__global__ void cvt_bf16(const float* __restrict__ x, unsigned short* __restrict__ xb) {
    int idx = blockIdx.x * 256 + threadIdx.x;
    if (idx >= N_NODES * D) return;
    xb[idx] = f2b(x[idx]);
}

// ---------------- CSR build over segments seg = dst*R + etype
__global__ void hist_k(const int* __restrict__ dst, const int* __restrict__ et, int* __restrict__ cnt) {
    int e = blockIdx.x * 256 + threadIdx.x;
    if (e >= N_EDGES) return;
    atomicAdd(&cnt[dst[e] * R_REL + et[e]], 1);
}

__global__ void scan_a(const int* __restrict__ cnt, int* __restrict__ bsum) {
    __shared__ int sm[256];
    int t = threadIdx.x;
    int idx = blockIdx.x * 256 + t;
    sm[t] = (idx < M_SEG) ? cnt[idx] : 0;
    __syncthreads();
    for (int s = 128; s > 0; s >>= 1) {
        if (t < s) sm[t] += sm[t + s];
        __syncthreads();
    }
    if (t == 0) bsum[blockIdx.x] = sm[0];
}

#define NB_SCAN 782  // ceil(200000/256)
__global__ void scan_b(const int* __restrict__ bsum, int* __restrict__ bsumex, int* __restrict__ offs) {
    __shared__ int sm[1024];
    int t = threadIdx.x;
    int v = (t < NB_SCAN) ? bsum[t] : 0;
    sm[t] = v;
    __syncthreads();
    for (int d = 1; d < 1024; d <<= 1) {
        int add = (t >= d) ? sm[t - d] : 0;
        __syncthreads();
        sm[t] += add;
        __syncthreads();
    }
    if (t < NB_SCAN) bsumex[t] = sm[t] - v;
    if (t == NB_SCAN - 1) offs[M_SEG] = sm[t];
}

__global__ void scan_c(const int* __restrict__ cnt, const int* __restrict__ bsumex, int* __restrict__ offs) {
    __shared__ int sm[256];
    int t = threadIdx.x;
    int idx = blockIdx.x * 256 + t;
    int v = (idx < M_SEG) ? cnt[idx] : 0;
    sm[t] = v;
    __syncthreads();
    for (int d = 1; d < 256; d <<= 1) {
        int add = (t >= d) ? sm[t - d] : 0;
        __syncthreads();
        sm[t] += add;
        __syncthreads();
    }
    if (idx < M_SEG) offs[idx] = bsumex[blockIdx.x] + sm[t] - v;
}

__global__ void scatter_k(const int* __restrict__ src, const int* __restrict__ dst,
                          const int* __restrict__ et, const int* __restrict__ offs,
                          int* __restrict__ tmp, int* __restrict__ esrc) {
    int e = blockIdx.x * 256 + threadIdx.x;
    if (e >= N_EDGES) return;
    int seg = dst[e] * R_REL + et[e];
    int pos = offs[seg] + atomicAdd(&tmp[seg], 1);
    esrc[pos] = src[e];
}

// ---------------- bf16 MFMA GEMM: C[N,384](f32) = A[N,128](bf16) @ B^T[384,128](bf16)
// BM=128, BN=128, 512 threads (8 waves, 2x4), 16x16x32 MFMA, K=128 (4 k-steps)
// LDS tiles [row][128 bf16] with XOR swizzle: uint4 slot = row*16 + (kk ^ (row&7))
__global__ __launch_bounds__(512) void gemm_mfma(const uint4* __restrict__ Aq,   // [M][16] rows of 8x bf16
                                                 const uint4* __restrict__ Bq,   // [384][16]
                                                 float* __restrict__ C) {
    __shared__ uint4 As[128 * 16];
    __shared__ uint4 Bs[128 * 16];
    int t = threadIdx.x;
    int m0 = blockIdx.x * 128;
    int n0 = blockIdx.y * 128;
#pragma unroll
    for (int i = 0; i < 4; ++i) {
        int idx = i * 512 + t;            // uint4 slot 0..2047
        int row = idx >> 4, kk = idx & 15;
        int gr = m0 + row;
        if (gr >= N_NODES) gr = N_NODES - 1;   // clamp; garbage rows skipped at store
        As[(row << 4) + (kk ^ (row & 7))] = Aq[gr * 16 + kk];
        Bs[(row << 4) + (kk ^ (row & 7))] = Bq[(n0 + row) * 16 + kk];
    }
    __syncthreads();
    int lane = t & 63, w = t >> 6;
    int wr = w >> 2, wc = w & 3;          // wave tile: rows wr*64.. cols wc*32..
    int lr = lane & 15, lh = lane >> 4;   // fragment lane coords
    f32x4 zero = {0.f, 0.f, 0.f, 0.f};
    f32x4 acc[4][2];
#pragma unroll
    for (int m = 0; m < 4; ++m)
#pragma unroll
        for (int n = 0; n < 2; ++n) acc[m][n] = zero;
#pragma unroll
    for (int ks = 0; ks < 4; ++ks) {
        short8v a[4], b[2];
#pragma unroll
        for (int m = 0; m < 4; ++m) {
            int row = wr * 64 + m * 16 + lr;
            a[m] = *reinterpret_cast<const short8v*>(&As[(row << 4) + ((ks * 4 + lh) ^ (row & 7))]);
        }
#pragma unroll
        for (int n = 0; n < 2; ++n) {
            int row = wc * 32 + n * 16 + lr;
            b[n] = *reinterpret_cast<const short8v*>(&Bs[(row << 4) + ((ks * 4 + lh) ^ (row & 7))]);
        }
#pragma unroll
        for (int m = 0; m < 4; ++m)
#pragma unroll
            for (int n = 0; n < 2; ++n)
                acc[m][n] = __builtin_amdgcn_mfma_f32_16x16x32_bf16(a[m], b[n], acc[m][n], 0, 0, 0);
    }
    // C/D layout: col = lane&15, row = (lane>>4)*4 + reg
#pragma unroll
    for (int m = 0; m < 4; ++m) {
#pragma unroll
        for (int reg = 0; reg < 4; ++reg) {
            int gr = m0 + wr * 64 + m * 16 + lh * 4 + reg;
            if (gr < N_NODES) {
#pragma unroll
                for (int n = 0; n < 2; ++n) {
                    int col = n0 + wc * 32 + n * 16 + lr;
                    C[(size_t)gr * NCOLS + col] = acc[m][n][reg];
                }
            }
        }
    }
}

// ---------------- self path: acc = relu(gamma_s * xsk + beta_s); buf cols: [0:128)=xsk,[128:256)=beta,[256:384)=gamma
__global__ void film_self(const float* __restrict__ buf, float* __restrict__ acc) {
    int idx = blockIdx.x * 256 + threadIdx.x;
    if (idx >= N_NODES * D) return;
    int n = idx >> 7, c = idx & 127;
    const float* row = buf + (size_t)n * NCOLS;
    float v = row[256 + c] * row[c] + row[128 + c];
    acc[idx] = fmaxf(v, 0.f);
}

// ---------------- per-relation aggregation: acc[n] += mean_e relu(gamma[n]*xr[src_e] + beta[n])
__global__ __launch_bounds__(128) void agg_rel(const float* __restrict__ buf, const int* __restrict__ offs,
                                               const int* __restrict__ esrc, float* __restrict__ acc, int r) {
    int n = blockIdx.x;
    int c = threadIdx.x;
    int seg = n * R_REL + r;
    int beg = offs[seg], end = offs[seg + 1];
    if (beg >= end) return;
    const float* row = buf + (size_t)n * NCOLS;
    float gamma = row[256 + c], beta = row[128 + c];
    float s = 0.f;
    for (int i = beg; i < end; ++i) {
        int src = esrc[i];
        s += fmaxf(gamma * buf[(size_t)src * NCOLS + c] + beta, 0.f);
    }
    acc[n * D + c] += s / (float)(end - beg);
}

// ---------------- batchnorm stats: coalesced, parallel
__global__ __launch_bounds__(256) void bn_stats2(const float* __restrict__ acc, float* __restrict__ sums) {
    __shared__ float sm[256], sm2[256];
    int t = threadIdx.x;
    int c = t & 127, half = t >> 7;
    int rows = (N_NODES + gridDim.x - 1) / gridDim.x;
    int nb = blockIdx.x * rows;
    int n1 = min(nb + rows, N_NODES);
    float s = 0.f, s2 = 0.f;
    for (int n = nb + half; n < n1; n += 2) {
        float v = acc[n * D + c];
        s += v;
        s2 += v * v;
    }
    sm[t] = s; sm2[t] = s2;
    __syncthreads();
    if (t < 128) {
        atomicAdd(&sums[c], sm[t] + sm[t + 128]);
        atomicAdd(&sums[128 + c], sm2[t] + sm2[t + 128]);
    }
}

// ---------------- batchnorm apply; also emits bf16 copy for next layer's GEMM input
__global__ void bn_apply(const float* __restrict__ acc, const float* __restrict__ sums,
                         const float* __restrict__ w, const float* __restrict__ b,
                         float* __restrict__ h, unsigned short* __restrict__ hb16) {
    int idx = blockIdx.x * 256 + threadIdx.x;
    if (idx >= N_NODES * D) return;
    int c = idx & 127;
    const float invn = 1.f / (float)N_NODES;
    float mu = sums[c] * invn;
    float var = sums[128 + c] * invn - mu * mu;
    float rs = rsqrtf(var + BN_EPS);
    float v = (acc[idx] - mu) * rs * w[c] + b[c];
    h[idx] = v;
    hb16[idx] = f2b(v);
}

// ---------------- head: out = leaky_relu(h@W1+b1, 0.2) @ W2 + b2
__global__ __launch_bounds__(128) void head_k(const float* __restrict__ h, const float* __restrict__ w1,
                                              const float* __restrict__ b1, const float* __restrict__ w2,
                                              const float* __restrict__ b2, float* __restrict__ out) {
    __shared__ float hrow[128];
    __shared__ float part[128];
    __shared__ float mid[32];
    int n = blockIdx.x, t = threadIdx.x;
    hrow[t] = h[n * D + t];
    __syncthreads();
    int m = t & 31, q = t >> 5;
    float p = 0.f;
#pragma unroll 8
    for (int k = q * 32; k < q * 32 + 32; ++k) p += hrow[k] * w1[k * 32 + m];
    part[t] = p;
    __syncthreads();
    if (t < 32) {
        float v = part[t] + part[t + 32] + part[t + 64] + part[t + 96] + b1[t];
        mid[t] = v > 0.f ? v : 0.2f * v;
    }
    __syncthreads();
    if (t < 40) {
        float o = b2[t];
#pragma unroll 8
        for (int mm = 0; mm < 32; ++mm) o += mid[mm] * w2[mm * 40 + t];
        out[n * 40 + t] = o;
    }
}

extern "C" void kernel_launch(void* const* d_in, const int* in_sizes, int n_in,
                              void* d_out, int out_size, void* d_ws, size_t ws_size,
                              hipStream_t stream) {
    const float* x    = (const float*)d_in[0];
    const int*   ei   = (const int*)d_in[1];
    const int*   et   = (const int*)d_in[2];
    const float* Wsk  = (const float*)d_in[3];
    const float* Wfsk = (const float*)d_in[4];
    const float* Wr   = (const float*)d_in[5];
    const float* Wf   = (const float*)d_in[6];
    const float* bnw  = (const float*)d_in[7];
    const float* bnb  = (const float*)d_in[8];
    const float* w1   = (const float*)d_in[9];
    const float* b1   = (const float*)d_in[10];
    const float* w2   = (const float*)d_in[11];
    const float* b2   = (const float*)d_in[12];
    const int* src = ei;
    const int* dst = ei + N_EDGES;

    char* ws = (char*)d_ws;
    size_t off = 0;
    auto alloc = [&](size_t bytes) -> void* {
        void* p = ws + off;
        off += (bytes + 255) & ~(size_t)255;
        return p;
    };
    unsigned short* Wpb  = (unsigned short*)alloc((size_t)L_LAYERS * 5 * NCOLS * D * 2);
    unsigned short* inb  = (unsigned short*)alloc((size_t)N_NODES * D * 2);   // bf16 GEMM input (x, then BN out)
    float* buf    = (float*)alloc((size_t)N_NODES * NCOLS * 4);
    float* acc    = (float*)alloc((size_t)N_NODES * D * 4);
    float* hbuf   = (float*)alloc((size_t)N_NODES * D * 4);
    int*   cnt    = (int*)alloc((size_t)M_SEG * 4);
    int*   offs   = (int*)alloc((size_t)(M_SEG + 1) * 4);
    int*   tmp    = (int*)alloc((size_t)M_SEG * 4);
    int*   esrc   = (int*)alloc((size_t)N_EDGES * 4);
    int*   bsum   = (int*)alloc(1024 * 4);
    int*   bsumex = (int*)alloc(1024 * 4);
    float* bns    = (float*)alloc(256 * 4);

    hipMemsetAsync(cnt, 0, (size_t)M_SEG * 4, stream);
    hipMemsetAsync(tmp, 0, (size_t)M_SEG * 4, stream);

    pack_w<<<(L_LAYERS * 5 * NCOLS * D + 255) / 256, 256, 0, stream>>>(Wsk, Wfsk, Wr, Wf, Wpb);
    cvt_bf16<<<(N_NODES * D + 255) / 256, 256, 0, stream>>>(x, inb);
    hist_k<<<(N_EDGES + 255) / 256, 256, 0, stream>>>(dst, et, cnt);
    scan_a<<<NB_SCAN, 256, 0, stream>>>(cnt, bsum);
    scan_b<<<1, 1024, 0, stream>>>(bsum, bsumex, offs);
    scan_c<<<NB_SCAN, 256, 0, stream>>>(cnt, bsumex, offs);
    scatter_k<<<(N_EDGES + 255) / 256, 256, 0, stream>>>(src, dst, et, offs, tmp, esrc);

    const int nbm = (N_NODES + 127) / 128;  // 391
    for (int l = 0; l < L_LAYERS; ++l) {
        const uint4* Aq = (const uint4*)inb;
        gemm_mfma<<<dim3(nbm, 3), 512, 0, stream>>>(Aq, (const uint4*)(Wpb + (size_t)(l * 5) * NCOLS * D), buf);
        film_self<<<(N_NODES * D + 255) / 256, 256, 0, stream>>>(buf, acc);
        for (int r = 0; r < R_REL; ++r) {
            gemm_mfma<<<dim3(nbm, 3), 512, 0, stream>>>(Aq, (const uint4*)(Wpb + (size_t)(l * 5 + 1 + r) * NCOLS * D), buf);
            agg_rel<<<N_NODES, 128, 0, stream>>>(buf, offs, esrc, acc, r);
        }
        hipMemsetAsync(bns, 0, 256 * 4, stream);
        bn_stats2<<<256, 256, 0, stream>>>(acc, bns);
        bn_apply<<<(N_NODES * D + 255) / 256, 256, 0, stream>>>(acc, bns, bnw + l * D, bnb + l * D, hbuf, inb);
    }
    head_k<<<N_NODES, 128, 0, stream>>>(hbuf, w1, b1, w2, b2, (float*)d_out);
}

// Round 3
// 926.896 us; speedup vs baseline: 2.3354x; 1.2491x over previous
//
#include <hip/hip_runtime.h>

#define N_NODES 50000
#define N_EDGES 800000
#define D 128
#define R_REL 4
#define L_LAYERS 3
#define M_SEG (N_NODES * R_REL)
#define NCOLS 384
#define BN_EPS 1e-5f

typedef unsigned short u16;
typedef __attribute__((ext_vector_type(8))) short short8v;
typedef __attribute__((ext_vector_type(4))) float f32x4;

static __device__ __forceinline__ u16 f2b(float f) {
    union { float f; unsigned int u; } a; a.f = f;
    unsigned int u = a.u;
    return (u16)((u + 0x7FFFu + ((u >> 16) & 1u)) >> 16);
}
static __device__ __forceinline__ float b2f(u16 b) {
    union { unsigned int u; float f; } a; a.u = ((unsigned int)b) << 16;
    return a.f;
}

// ---------------- weight packing: Wpb[(l*5+p)][j=0..383][k=0..127] bf16 (transposed)
__global__ void pack_w(const float* __restrict__ Wsk, const float* __restrict__ Wfsk,
                       const float* __restrict__ Wr, const float* __restrict__ Wf,
                       u16* __restrict__ Wpb) {
    int idx = blockIdx.x * 256 + threadIdx.x;
    if (idx >= L_LAYERS * 5 * NCOLS * D) return;
    int k = idx & 127;
    int rem = idx >> 7;
    int j = rem % NCOLS;
    int lp = rem / NCOLS;
    int l = lp / 5, p = lp % 5;
    float v;
    if (p == 0) {
        v = (j < D) ? Wsk[(l * D + k) * D + j] : Wfsk[(l * D + k) * 2 * D + (j - D)];
    } else {
        int r = p - 1;
        v = (j < D) ? Wr[((l * R_REL + r) * D + k) * D + j]
                    : Wf[((l * R_REL + r) * D + k) * 2 * D + (j - D)];
    }
    Wpb[idx] = f2b(v);
}

__global__ void cvt_bf16(const float* __restrict__ x, u16* __restrict__ xb) {
    int idx = blockIdx.x * 256 + threadIdx.x;
    if (idx >= N_NODES * D) return;
    xb[idx] = f2b(x[idx]);
}

// ---------------- CSR build over segments seg = dst*R + etype
__global__ void hist_k(const int* __restrict__ dst, const int* __restrict__ et, int* __restrict__ cnt) {
    int e = blockIdx.x * 256 + threadIdx.x;
    if (e >= N_EDGES) return;
    atomicAdd(&cnt[dst[e] * R_REL + et[e]], 1);
}

__global__ void scan_a(const int* __restrict__ cnt, int* __restrict__ bsum) {
    __shared__ int sm[256];
    int t = threadIdx.x;
    int idx = blockIdx.x * 256 + t;
    sm[t] = (idx < M_SEG) ? cnt[idx] : 0;
    __syncthreads();
    for (int s = 128; s > 0; s >>= 1) {
        if (t < s) sm[t] += sm[t + s];
        __syncthreads();
    }
    if (t == 0) bsum[blockIdx.x] = sm[0];
}

#define NB_SCAN 782  // ceil(200000/256)
__global__ void scan_b(const int* __restrict__ bsum, int* __restrict__ bsumex, int* __restrict__ offs) {
    __shared__ int sm[1024];
    int t = threadIdx.x;
    int v = (t < NB_SCAN) ? bsum[t] : 0;
    sm[t] = v;
    __syncthreads();
    for (int d = 1; d < 1024; d <<= 1) {
        int add = (t >= d) ? sm[t - d] : 0;
        __syncthreads();
        sm[t] += add;
        __syncthreads();
    }
    if (t < NB_SCAN) bsumex[t] = sm[t] - v;
    if (t == NB_SCAN - 1) offs[M_SEG] = sm[t];
}

__global__ void scan_c(const int* __restrict__ cnt, const int* __restrict__ bsumex, int* __restrict__ offs) {
    __shared__ int sm[256];
    int t = threadIdx.x;
    int idx = blockIdx.x * 256 + t;
    int v = (idx < M_SEG) ? cnt[idx] : 0;
    sm[t] = v;
    __syncthreads();
    for (int d = 1; d < 256; d <<= 1) {
        int add = (t >= d) ? sm[t - d] : 0;
        __syncthreads();
        sm[t] += add;
        __syncthreads();
    }
    if (idx < M_SEG) offs[idx] = bsumex[blockIdx.x] + sm[t] - v;
}

__global__ void scatter_k(const int* __restrict__ src, const int* __restrict__ dst,
                          const int* __restrict__ et, const int* __restrict__ offs,
                          int* __restrict__ tmp, int* __restrict__ esrc) {
    int e = blockIdx.x * 256 + threadIdx.x;
    if (e >= N_EDGES) return;
    int seg = dst[e] * R_REL + et[e];
    int pos = offs[seg] + atomicAdd(&tmp[seg], 1);
    esrc[pos] = src[e];
}

// ---------------- bf16 MFMA GEMM: C[N,384](bf16) = A[N,128](bf16) @ B^T[384,128](bf16)
// BM=128, BN=128, 512 threads (8 waves, 2x4), 16x16x32 MFMA, K=128 (4 k-steps)
__global__ __launch_bounds__(512) void gemm_mfma(const uint4* __restrict__ Aq,   // [M][16] rows of 8x bf16
                                                 const uint4* __restrict__ Bq,   // [384][16]
                                                 u16* __restrict__ C) {
    __shared__ uint4 As[128 * 16];
    __shared__ uint4 Bs[128 * 16];
    int t = threadIdx.x;
    int m0 = blockIdx.x * 128;
    int n0 = blockIdx.y * 128;
#pragma unroll
    for (int i = 0; i < 4; ++i) {
        int idx = i * 512 + t;
        int row = idx >> 4, kk = idx & 15;
        int gr = m0 + row;
        if (gr >= N_NODES) gr = N_NODES - 1;
        As[(row << 4) + (kk ^ (row & 7))] = Aq[gr * 16 + kk];
        Bs[(row << 4) + (kk ^ (row & 7))] = Bq[(n0 + row) * 16 + kk];
    }
    __syncthreads();
    int lane = t & 63, w = t >> 6;
    int wr = w >> 2, wc = w & 3;
    int lr = lane & 15, lh = lane >> 4;
    f32x4 zero = {0.f, 0.f, 0.f, 0.f};
    f32x4 acc[4][2];
#pragma unroll
    for (int m = 0; m < 4; ++m)
#pragma unroll
        for (int n = 0; n < 2; ++n) acc[m][n] = zero;
#pragma unroll
    for (int ks = 0; ks < 4; ++ks) {
        short8v a[4], b[2];
#pragma unroll
        for (int m = 0; m < 4; ++m) {
            int row = wr * 64 + m * 16 + lr;
            a[m] = *reinterpret_cast<const short8v*>(&As[(row << 4) + ((ks * 4 + lh) ^ (row & 7))]);
        }
#pragma unroll
        for (int n = 0; n < 2; ++n) {
            int row = wc * 32 + n * 16 + lr;
            b[n] = *reinterpret_cast<const short8v*>(&Bs[(row << 4) + ((ks * 4 + lh) ^ (row & 7))]);
        }
#pragma unroll
        for (int m = 0; m < 4; ++m)
#pragma unroll
            for (int n = 0; n < 2; ++n)
                acc[m][n] = __builtin_amdgcn_mfma_f32_16x16x32_bf16(a[m], b[n], acc[m][n], 0, 0, 0);
    }
#pragma unroll
    for (int m = 0; m < 4; ++m) {
#pragma unroll
        for (int reg = 0; reg < 4; ++reg) {
            int gr = m0 + wr * 64 + m * 16 + lh * 4 + reg;
            if (gr < N_NODES) {
#pragma unroll
                for (int n = 0; n < 2; ++n) {
                    int col = n0 + wc * 32 + n * 16 + lr;
                    C[(size_t)gr * NCOLS + col] = f2b(acc[m][n][reg]);
                }
            }
        }
    }
}

// ---------------- FUSED per-node: film_self + 4 relation segment-means -> acc (write once)
__global__ __launch_bounds__(128) void film_agg(const u16* __restrict__ bufS,
                                                const u16* __restrict__ buf0, const u16* __restrict__ buf1,
                                                const u16* __restrict__ buf2, const u16* __restrict__ buf3,
                                                const int* __restrict__ offs, const int* __restrict__ esrc,
                                                float* __restrict__ acc) {
    int n = blockIdx.x, c = threadIdx.x;
    const u16* row = bufS + (size_t)n * NCOLS;
    float h = fmaxf(b2f(row[256 + c]) * b2f(row[c]) + b2f(row[128 + c]), 0.f);
    const u16* bufs[4] = {buf0, buf1, buf2, buf3};
#pragma unroll
    for (int r = 0; r < R_REL; ++r) {
        const u16* B = bufs[r];
        int seg = n * R_REL + r;
        int beg = offs[seg], end = offs[seg + 1];
        if (beg < end) {
            const u16* grow = B + (size_t)n * NCOLS;
            float g = b2f(grow[256 + c]), be = b2f(grow[128 + c]);
            float s = 0.f;
            for (int i = beg; i < end; ++i)
                s += fmaxf(g * b2f(B[(size_t)esrc[i] * NCOLS + c]) + be, 0.f);
            h += s / (float)(end - beg);
        }
    }
    acc[n * D + c] = h;
}

// ---------------- fallback (single buf): film_self + per-relation agg
__global__ void film_self_b(const u16* __restrict__ buf, float* __restrict__ acc) {
    int idx = blockIdx.x * 256 + threadIdx.x;
    if (idx >= N_NODES * D) return;
    int n = idx >> 7, c = idx & 127;
    const u16* row = buf + (size_t)n * NCOLS;
    acc[idx] = fmaxf(b2f(row[256 + c]) * b2f(row[c]) + b2f(row[128 + c]), 0.f);
}

__global__ __launch_bounds__(128) void agg_rel_b(const u16* __restrict__ buf, const int* __restrict__ offs,
                                                 const int* __restrict__ esrc, float* __restrict__ acc, int r) {
    int n = blockIdx.x;
    int c = threadIdx.x;
    int seg = n * R_REL + r;
    int beg = offs[seg], end = offs[seg + 1];
    if (beg >= end) return;
    const u16* row = buf + (size_t)n * NCOLS;
    float g = b2f(row[256 + c]), be = b2f(row[128 + c]);
    float s = 0.f;
    for (int i = beg; i < end; ++i)
        s += fmaxf(g * b2f(buf[(size_t)esrc[i] * NCOLS + c]) + be, 0.f);
    acc[n * D + c] += s / (float)(end - beg);
}

// ---------------- batchnorm stats: coalesced, parallel
__global__ __launch_bounds__(256) void bn_stats2(const float* __restrict__ acc, float* __restrict__ sums) {
    __shared__ float sm[256], sm2[256];
    int t = threadIdx.x;
    int c = t & 127, half = t >> 7;
    int rows = (N_NODES + gridDim.x - 1) / gridDim.x;
    int nb = blockIdx.x * rows;
    int n1 = min(nb + rows, N_NODES);
    float s = 0.f, s2 = 0.f;
    for (int n = nb + half; n < n1; n += 2) {
        float v = acc[n * D + c];
        s += v;
        s2 += v * v;
    }
    sm[t] = s; sm2[t] = s2;
    __syncthreads();
    if (t < 128) {
        atomicAdd(&sums[c], sm[t] + sm[t + 128]);
        atomicAdd(&sums[128 + c], sm2[t] + sm2[t + 128]);
    }
}

// ---------------- batchnorm apply -> bf16 next-layer input
__global__ void bn_apply(const float* __restrict__ acc, const float* __restrict__ sums,
                         const float* __restrict__ w, const float* __restrict__ b,
                         u16* __restrict__ hb16) {
    int idx = blockIdx.x * 256 + threadIdx.x;
    if (idx >= N_NODES * D) return;
    int c = idx & 127;
    const float invn = 1.f / (float)N_NODES;
    float mu = sums[c] * invn;
    float var = sums[128 + c] * invn - mu * mu;
    float rs = rsqrtf(var + BN_EPS);
    hb16[idx] = f2b((acc[idx] - mu) * rs * w[c] + b[c]);
}

// ---------------- head: out = leaky_relu(h@W1+b1, 0.2) @ W2 + b2  (h is bf16)
__global__ __launch_bounds__(128) void head_k(const u16* __restrict__ h, const float* __restrict__ w1,
                                              const float* __restrict__ b1, const float* __restrict__ w2,
                                              const float* __restrict__ b2, float* __restrict__ out) {
    __shared__ float hrow[128];
    __shared__ float part[128];
    __shared__ float mid[32];
    int n = blockIdx.x, t = threadIdx.x;
    hrow[t] = b2f(h[n * D + t]);
    __syncthreads();
    int m = t & 31, q = t >> 5;
    float p = 0.f;
#pragma unroll 8
    for (int k = q * 32; k < q * 32 + 32; ++k) p += hrow[k] * w1[k * 32 + m];
    part[t] = p;
    __syncthreads();
    if (t < 32) {
        float v = part[t] + part[t + 32] + part[t + 64] + part[t + 96] + b1[t];
        mid[t] = v > 0.f ? v : 0.2f * v;
    }
    __syncthreads();
    if (t < 40) {
        float o = b2[t];
#pragma unroll 8
        for (int mm = 0; mm < 32; ++mm) o += mid[mm] * w2[mm * 40 + t];
        out[n * 40 + t] = o;
    }
}

extern "C" void kernel_launch(void* const* d_in, const int* in_sizes, int n_in,
                              void* d_out, int out_size, void* d_ws, size_t ws_size,
                              hipStream_t stream) {
    const float* x    = (const float*)d_in[0];
    const int*   ei   = (const int*)d_in[1];
    const int*   et   = (const int*)d_in[2];
    const float* Wsk  = (const float*)d_in[3];
    const float* Wfsk = (const float*)d_in[4];
    const float* Wr   = (const float*)d_in[5];
    const float* Wf   = (const float*)d_in[6];
    const float* bnw  = (const float*)d_in[7];
    const float* bnb  = (const float*)d_in[8];
    const float* w1   = (const float*)d_in[9];
    const float* b1   = (const float*)d_in[10];
    const float* w2   = (const float*)d_in[11];
    const float* b2   = (const float*)d_in[12];
    const int* src = ei;
    const int* dst = ei + N_EDGES;

    char* ws = (char*)d_ws;
    size_t off = 0;
    auto alloc = [&](size_t bytes) -> void* {
        void* p = ws + off;
        off += (bytes + 255) & ~(size_t)255;
        return p;
    };
    const size_t BUF_B = (size_t)N_NODES * NCOLS * 2;  // 38.4 MB bf16
    u16*   Wpb  = (u16*)alloc((size_t)L_LAYERS * 5 * NCOLS * D * 2);
    u16*   inb  = (u16*)alloc((size_t)N_NODES * D * 2);
    float* acc  = (float*)alloc((size_t)N_NODES * D * 4);
    int*   cnt    = (int*)alloc((size_t)M_SEG * 4);     // these three contiguous:
    int*   tmp    = (int*)alloc((size_t)M_SEG * 4);     // one memset covers cnt+tmp+bns
    float* bns    = (float*)alloc((size_t)L_LAYERS * 256 * 4);
    int*   offs   = (int*)alloc((size_t)(M_SEG + 1) * 4);
    int*   esrc   = (int*)alloc((size_t)N_EDGES * 4);
    int*   bsum   = (int*)alloc(1024 * 4);
    int*   bsumex = (int*)alloc(1024 * 4);
    size_t base_off = off;
    // big path: 5 bufs; small path: 1 buf
    bool big = (base_off + 5 * ((BUF_B + 255) & ~(size_t)255)) <= ws_size;
    u16* bufS = (u16*)alloc(BUF_B);
    u16* bufR[4];
    for (int r = 0; r < 4; ++r) bufR[r] = big ? (u16*)alloc(BUF_B) : bufS;

    hipMemsetAsync(cnt, 0, (size_t)M_SEG * 8 + (size_t)L_LAYERS * 1024, stream);

    pack_w<<<(L_LAYERS * 5 * NCOLS * D + 255) / 256, 256, 0, stream>>>(Wsk, Wfsk, Wr, Wf, Wpb);
    cvt_bf16<<<(N_NODES * D + 255) / 256, 256, 0, stream>>>(x, inb);
    hist_k<<<(N_EDGES + 255) / 256, 256, 0, stream>>>(dst, et, cnt);
    scan_a<<<NB_SCAN, 256, 0, stream>>>(cnt, bsum);
    scan_b<<<1, 1024, 0, stream>>>(bsum, bsumex, offs);
    scan_c<<<NB_SCAN, 256, 0, stream>>>(cnt, bsumex, offs);
    scatter_k<<<(N_EDGES + 255) / 256, 256, 0, stream>>>(src, dst, et, offs, tmp, esrc);

    const int nbm = (N_NODES + 127) / 128;  // 391
    for (int l = 0; l < L_LAYERS; ++l) {
        const uint4* Aq = (const uint4*)inb;
        const uint4* Wl = (const uint4*)(Wpb + (size_t)(l * 5) * NCOLS * D);
        if (big) {
            gemm_mfma<<<dim3(nbm, 3), 512, 0, stream>>>(Aq, Wl, bufS);
            for (int r = 0; r < R_REL; ++r)
                gemm_mfma<<<dim3(nbm, 3), 512, 0, stream>>>(
                    Aq, (const uint4*)(Wpb + (size_t)(l * 5 + 1 + r) * NCOLS * D), bufR[r]);
            film_agg<<<N_NODES, 128, 0, stream>>>(bufS, bufR[0], bufR[1], bufR[2], bufR[3], offs, esrc, acc);
        } else {
            gemm_mfma<<<dim3(nbm, 3), 512, 0, stream>>>(Aq, Wl, bufS);
            film_self_b<<<(N_NODES * D + 255) / 256, 256, 0, stream>>>(bufS, acc);
            for (int r = 0; r < R_REL; ++r) {
                gemm_mfma<<<dim3(nbm, 3), 512, 0, stream>>>(
                    Aq, (const uint4*)(Wpb + (size_t)(l * 5 + 1 + r) * NCOLS * D), bufS);
                agg_rel_b<<<N_NODES, 128, 0, stream>>>(bufS, offs, esrc, acc, r);
            }
        }
        bn_stats2<<<256, 256, 0, stream>>>(acc, bns + l * 256);
        bn_apply<<<(N_NODES * D + 255) / 256, 256, 0, stream>>>(acc, bns + l * 256, bnw + l * D, bnb + l * D, inb);
    }
    head_k<<<N_NODES, 128, 0, stream>>>(inb, w1, b1, w2, b2, (float*)d_out);
}

// Round 4
// 836.149 us; speedup vs baseline: 2.5888x; 1.1085x over previous
//
#include <hip/hip_runtime.h>

#define N_NODES 50000
#define N_EDGES 800000
#define D 128
#define R_REL 4
#define L_LAYERS 3
#define M_SEG (N_NODES * R_REL)
#define NCOLS 384
#define BN_EPS 1e-5f

typedef unsigned short u16;
typedef __attribute__((ext_vector_type(8))) short short8v;
typedef __attribute__((ext_vector_type(4))) float f32x4;

static __device__ __forceinline__ u16 f2b(float f) {
    union { float f; unsigned int u; } a; a.f = f;
    unsigned int u = a.u;
    return (u16)((u + 0x7FFFu + ((u >> 16) & 1u)) >> 16);
}
static __device__ __forceinline__ float b2f(u16 b) {
    union { unsigned int u; float f; } a; a.u = ((unsigned int)b) << 16;
    return a.f;
}

// ---------------- weight packing: Wpb[(l*5+p)][j=0..383][k=0..127] bf16 (transposed)
__global__ void pack_w(const float* __restrict__ Wsk, const float* __restrict__ Wfsk,
                       const float* __restrict__ Wr, const float* __restrict__ Wf,
                       u16* __restrict__ Wpb) {
    int idx = blockIdx.x * 256 + threadIdx.x;
    if (idx >= L_LAYERS * 5 * NCOLS * D) return;
    int k = idx & 127;
    int rem = idx >> 7;
    int j = rem % NCOLS;
    int lp = rem / NCOLS;
    int l = lp / 5, p = lp % 5;
    float v;
    if (p == 0) {
        v = (j < D) ? Wsk[(l * D + k) * D + j] : Wfsk[(l * D + k) * 2 * D + (j - D)];
    } else {
        int r = p - 1;
        v = (j < D) ? Wr[((l * R_REL + r) * D + k) * D + j]
                    : Wf[((l * R_REL + r) * D + k) * 2 * D + (j - D)];
    }
    Wpb[idx] = f2b(v);
}

__global__ void cvt_bf16(const float* __restrict__ x, u16* __restrict__ xb) {
    int idx = blockIdx.x * 256 + threadIdx.x;
    if (idx >= N_NODES * D) return;
    xb[idx] = f2b(x[idx]);
}

// ---------------- CSR build over segments seg = dst*R + etype
__global__ void hist_k(const int* __restrict__ dst, const int* __restrict__ et, int* __restrict__ cnt) {
    int e = blockIdx.x * 256 + threadIdx.x;
    if (e >= N_EDGES) return;
    atomicAdd(&cnt[dst[e] * R_REL + et[e]], 1);
}

__global__ void scan_a(const int* __restrict__ cnt, int* __restrict__ bsum) {
    __shared__ int sm[256];
    int t = threadIdx.x;
    int idx = blockIdx.x * 256 + t;
    sm[t] = (idx < M_SEG) ? cnt[idx] : 0;
    __syncthreads();
    for (int s = 128; s > 0; s >>= 1) {
        if (t < s) sm[t] += sm[t + s];
        __syncthreads();
    }
    if (t == 0) bsum[blockIdx.x] = sm[0];
}

#define NB_SCAN 782  // ceil(200000/256)
__global__ void scan_b(const int* __restrict__ bsum, int* __restrict__ bsumex, int* __restrict__ offs) {
    __shared__ int sm[1024];
    int t = threadIdx.x;
    int v = (t < NB_SCAN) ? bsum[t] : 0;
    sm[t] = v;
    __syncthreads();
    for (int d = 1; d < 1024; d <<= 1) {
        int add = (t >= d) ? sm[t - d] : 0;
        __syncthreads();
        sm[t] += add;
        __syncthreads();
    }
    if (t < NB_SCAN) bsumex[t] = sm[t] - v;
    if (t == NB_SCAN - 1) offs[M_SEG] = sm[t];
}

__global__ void scan_c(const int* __restrict__ cnt, const int* __restrict__ bsumex, int* __restrict__ offs) {
    __shared__ int sm[256];
    int t = threadIdx.x;
    int idx = blockIdx.x * 256 + t;
    int v = (idx < M_SEG) ? cnt[idx] : 0;
    sm[t] = v;
    __syncthreads();
    for (int d = 1; d < 256; d <<= 1) {
        int add = (t >= d) ? sm[t - d] : 0;
        __syncthreads();
        sm[t] += add;
        __syncthreads();
    }
    if (idx < M_SEG) offs[idx] = bsumex[blockIdx.x] + sm[t] - v;
}

__global__ void scatter_k(const int* __restrict__ src, const int* __restrict__ dst,
                          const int* __restrict__ et, const int* __restrict__ offs,
                          int* __restrict__ tmp, int* __restrict__ esrc) {
    int e = blockIdx.x * 256 + threadIdx.x;
    if (e >= N_EDGES) return;
    int seg = dst[e] * R_REL + et[e];
    int pos = offs[seg] + atomicAdd(&tmp[seg], 1);
    esrc[pos] = src[e];
}

// ---------------- fused per-layer GEMM: for p in 0..4: Call[p][N][384] = A @ Wp^T
// grid (391, 5), 512 threads (8 waves 2x4). A-tile 128x128 staged once (32KB LDS, XOR swizzle),
// A-fragments kept in registers across the 3 col-chunks; B read direct from global (L2-hot).
__global__ __launch_bounds__(512) void gemm5(const uint4* __restrict__ Aq,   // [N][16] rows of 8x bf16
                                             const uint4* __restrict__ Bq,   // layer base: [5*384][16]
                                             u16* __restrict__ Call) {
    __shared__ uint4 As[128 * 16];
    int t = threadIdx.x;
    int m0 = blockIdx.x * 128;
    int p = blockIdx.y;
#pragma unroll
    for (int i = 0; i < 4; ++i) {
        int idx = i * 512 + t;
        int row = idx >> 4, kk = idx & 15;
        int gr = m0 + row;
        if (gr >= N_NODES) gr = N_NODES - 1;
        As[(row << 4) + (kk ^ (row & 7))] = Aq[gr * 16 + kk];
    }
    __syncthreads();
    int lane = t & 63, w = t >> 6;
    int wr = w >> 2, wc = w & 3;
    int lr = lane & 15, lh = lane >> 4;
    // A fragments once: a[m][ks]
    short8v a[4][4];
#pragma unroll
    for (int m = 0; m < 4; ++m) {
        int row = wr * 64 + m * 16 + lr;
#pragma unroll
        for (int ks = 0; ks < 4; ++ks)
            a[m][ks] = *reinterpret_cast<const short8v*>(&As[(row << 4) + ((ks * 4 + lh) ^ (row & 7))]);
    }
    const uint4* Bp = Bq + (size_t)p * NCOLS * 16;
    u16* Cp = Call + (size_t)p * N_NODES * NCOLS;
    f32x4 zero = {0.f, 0.f, 0.f, 0.f};
#pragma unroll
    for (int chunk = 0; chunk < 3; ++chunk) {
        int n0 = chunk * 128;
        f32x4 acc[4][2];
#pragma unroll
        for (int m = 0; m < 4; ++m)
#pragma unroll
            for (int n = 0; n < 2; ++n) acc[m][n] = zero;
#pragma unroll
        for (int ks = 0; ks < 4; ++ks) {
            short8v b[2];
#pragma unroll
            for (int n = 0; n < 2; ++n) {
                int row = n0 + wc * 32 + n * 16 + lr;
                b[n] = *reinterpret_cast<const short8v*>(&Bp[row * 16 + ks * 4 + lh]);
            }
#pragma unroll
            for (int m = 0; m < 4; ++m)
#pragma unroll
                for (int n = 0; n < 2; ++n)
                    acc[m][n] = __builtin_amdgcn_mfma_f32_16x16x32_bf16(a[m][ks], b[n], acc[m][n], 0, 0, 0);
        }
#pragma unroll
        for (int m = 0; m < 4; ++m) {
#pragma unroll
            for (int reg = 0; reg < 4; ++reg) {
                int gr = m0 + wr * 64 + m * 16 + lh * 4 + reg;
                if (gr < N_NODES) {
#pragma unroll
                    for (int n = 0; n < 2; ++n) {
                        int col = n0 + wc * 32 + n * 16 + lr;
                        Cp[(size_t)gr * NCOLS + col] = f2b(acc[m][n][reg]);
                    }
                }
            }
        }
    }
}

// ---------------- FUSED per-node film+agg: wave per node, ushort4 loads, half-wave edge split
__global__ __launch_bounds__(256) void film_agg2(const u16* __restrict__ bufAll,
                                                 const int* __restrict__ offs, const int* __restrict__ esrc,
                                                 float* __restrict__ acc) {
    int t = threadIdx.x;
    int n = blockIdx.x * 4 + (t >> 6);
    int lane = t & 63;
    int cg = (lane & 31) * 4;       // 4 columns per lane
    int half = lane >> 5;           // half-wave edge split
    const u16* rowS = bufAll + (size_t)n * NCOLS;
    ushort4 xs = *reinterpret_cast<const ushort4*>(&rowS[cg]);
    ushort4 bs = *reinterpret_cast<const ushort4*>(&rowS[128 + cg]);
    ushort4 gs = *reinterpret_cast<const ushort4*>(&rowS[256 + cg]);
    float h0 = fmaxf(b2f(gs.x) * b2f(xs.x) + b2f(bs.x), 0.f);
    float h1 = fmaxf(b2f(gs.y) * b2f(xs.y) + b2f(bs.y), 0.f);
    float h2 = fmaxf(b2f(gs.z) * b2f(xs.z) + b2f(bs.z), 0.f);
    float h3 = fmaxf(b2f(gs.w) * b2f(xs.w) + b2f(bs.w), 0.f);
#pragma unroll
    for (int r = 0; r < R_REL; ++r) {
        const u16* B = bufAll + (size_t)(1 + r) * N_NODES * NCOLS;
        int seg = n * R_REL + r;
        int beg = offs[seg], end = offs[seg + 1];
        if (beg < end) {
            const u16* grow = B + (size_t)n * NCOLS;
            ushort4 b4 = *reinterpret_cast<const ushort4*>(&grow[128 + cg]);
            ushort4 g4 = *reinterpret_cast<const ushort4*>(&grow[256 + cg]);
            float g0 = b2f(g4.x), g1 = b2f(g4.y), g2 = b2f(g4.z), g3 = b2f(g4.w);
            float be0 = b2f(b4.x), be1 = b2f(b4.y), be2 = b2f(b4.z), be3 = b2f(b4.w);
            float s0 = 0.f, s1 = 0.f, s2 = 0.f, s3 = 0.f;
            for (int i = beg + half; i < end; i += 2) {
                int src = esrc[i];
                ushort4 x4 = *reinterpret_cast<const ushort4*>(&B[(size_t)src * NCOLS + cg]);
                s0 += fmaxf(g0 * b2f(x4.x) + be0, 0.f);
                s1 += fmaxf(g1 * b2f(x4.y) + be1, 0.f);
                s2 += fmaxf(g2 * b2f(x4.z) + be2, 0.f);
                s3 += fmaxf(g3 * b2f(x4.w) + be3, 0.f);
            }
            s0 += __shfl_xor(s0, 32);
            s1 += __shfl_xor(s1, 32);
            s2 += __shfl_xor(s2, 32);
            s3 += __shfl_xor(s3, 32);
            float inv = 1.f / (float)(end - beg);
            h0 += s0 * inv; h1 += s1 * inv; h2 += s2 * inv; h3 += s3 * inv;
        }
    }
    if (half == 0) {
        float4 o = make_float4(h0, h1, h2, h3);
        *reinterpret_cast<float4*>(&acc[(size_t)n * D + cg]) = o;
    }
}

// ---------------- batchnorm stats
__global__ __launch_bounds__(256) void bn_stats2(const float* __restrict__ acc, float* __restrict__ sums) {
    __shared__ float sm[256], sm2[256];
    int t = threadIdx.x;
    int c = t & 127, half = t >> 7;
    int rows = (N_NODES + gridDim.x - 1) / gridDim.x;
    int nb = blockIdx.x * rows;
    int n1 = min(nb + rows, N_NODES);
    float s = 0.f, s2 = 0.f;
    for (int n = nb + half; n < n1; n += 2) {
        float v = acc[n * D + c];
        s += v;
        s2 += v * v;
    }
    sm[t] = s; sm2[t] = s2;
    __syncthreads();
    if (t < 128) {
        atomicAdd(&sums[c], sm[t] + sm[t + 128]);
        atomicAdd(&sums[128 + c], sm2[t] + sm2[t + 128]);
    }
}

// ---------------- batchnorm apply -> bf16 next-layer input
__global__ void bn_apply(const float* __restrict__ acc, const float* __restrict__ sums,
                         const float* __restrict__ w, const float* __restrict__ b,
                         u16* __restrict__ hb16) {
    int idx = blockIdx.x * 256 + threadIdx.x;
    if (idx >= N_NODES * D) return;
    int c = idx & 127;
    const float invn = 1.f / (float)N_NODES;
    float mu = sums[c] * invn;
    float var = sums[128 + c] * invn - mu * mu;
    float rs = rsqrtf(var + BN_EPS);
    hb16[idx] = f2b((acc[idx] - mu) * rs * w[c] + b[c]);
}

// ---------------- head
__global__ __launch_bounds__(128) void head_k(const u16* __restrict__ h, const float* __restrict__ w1,
                                              const float* __restrict__ b1, const float* __restrict__ w2,
                                              const float* __restrict__ b2, float* __restrict__ out) {
    __shared__ float hrow[128];
    __shared__ float part[128];
    __shared__ float mid[32];
    int n = blockIdx.x, t = threadIdx.x;
    hrow[t] = b2f(h[n * D + t]);
    __syncthreads();
    int m = t & 31, q = t >> 5;
    float p = 0.f;
#pragma unroll 8
    for (int k = q * 32; k < q * 32 + 32; ++k) p += hrow[k] * w1[k * 32 + m];
    part[t] = p;
    __syncthreads();
    if (t < 32) {
        float v = part[t] + part[t + 32] + part[t + 64] + part[t + 96] + b1[t];
        mid[t] = v > 0.f ? v : 0.2f * v;
    }
    __syncthreads();
    if (t < 40) {
        float o = b2[t];
#pragma unroll 8
        for (int mm = 0; mm < 32; ++mm) o += mid[mm] * w2[mm * 40 + t];
        out[n * 40 + t] = o;
    }
}

extern "C" void kernel_launch(void* const* d_in, const int* in_sizes, int n_in,
                              void* d_out, int out_size, void* d_ws, size_t ws_size,
                              hipStream_t stream) {
    const float* x    = (const float*)d_in[0];
    const int*   ei   = (const int*)d_in[1];
    const int*   et   = (const int*)d_in[2];
    const float* Wsk  = (const float*)d_in[3];
    const float* Wfsk = (const float*)d_in[4];
    const float* Wr   = (const float*)d_in[5];
    const float* Wf   = (const float*)d_in[6];
    const float* bnw  = (const float*)d_in[7];
    const float* bnb  = (const float*)d_in[8];
    const float* w1   = (const float*)d_in[9];
    const float* b1   = (const float*)d_in[10];
    const float* w2   = (const float*)d_in[11];
    const float* b2   = (const float*)d_in[12];
    const int* src = ei;
    const int* dst = ei + N_EDGES;

    char* ws = (char*)d_ws;
    size_t off = 0;
    auto alloc = [&](size_t bytes) -> void* {
        void* p = ws + off;
        off += (bytes + 255) & ~(size_t)255;
        return p;
    };
    u16*   Wpb  = (u16*)alloc((size_t)L_LAYERS * 5 * NCOLS * D * 2);
    u16*   inb  = (u16*)alloc((size_t)N_NODES * D * 2);
    float* acc  = (float*)alloc((size_t)N_NODES * D * 4);
    int*   cnt    = (int*)alloc((size_t)M_SEG * 4);     // contiguous with tmp+bns: one memset
    int*   tmp    = (int*)alloc((size_t)M_SEG * 4);
    float* bns    = (float*)alloc((size_t)L_LAYERS * 256 * 4);
    int*   offs   = (int*)alloc((size_t)(M_SEG + 1) * 4);
    int*   esrc   = (int*)alloc((size_t)N_EDGES * 4);
    int*   bsum   = (int*)alloc(1024 * 4);
    int*   bsumex = (int*)alloc(1024 * 4);
    u16*   bufAll = (u16*)alloc((size_t)5 * N_NODES * NCOLS * 2);  // 192 MB: 5 planes [N][384]

    hipMemsetAsync(cnt, 0, (size_t)M_SEG * 8 + (size_t)L_LAYERS * 1024, stream);

    pack_w<<<(L_LAYERS * 5 * NCOLS * D + 255) / 256, 256, 0, stream>>>(Wsk, Wfsk, Wr, Wf, Wpb);
    cvt_bf16<<<(N_NODES * D + 255) / 256, 256, 0, stream>>>(x, inb);
    hist_k<<<(N_EDGES + 255) / 256, 256, 0, stream>>>(dst, et, cnt);
    scan_a<<<NB_SCAN, 256, 0, stream>>>(cnt, bsum);
    scan_b<<<1, 1024, 0, stream>>>(bsum, bsumex, offs);
    scan_c<<<NB_SCAN, 256, 0, stream>>>(cnt, bsumex, offs);
    scatter_k<<<(N_EDGES + 255) / 256, 256, 0, stream>>>(src, dst, et, offs, tmp, esrc);

    const int nbm = (N_NODES + 127) / 128;  // 391
    for (int l = 0; l < L_LAYERS; ++l) {
        gemm5<<<dim3(nbm, 5), 512, 0, stream>>>((const uint4*)inb,
                                                (const uint4*)(Wpb + (size_t)(l * 5) * NCOLS * D), bufAll);
        film_agg2<<<N_NODES / 4, 256, 0, stream>>>(bufAll, offs, esrc, acc);
        bn_stats2<<<256, 256, 0, stream>>>(acc, bns + l * 256);
        bn_apply<<<(N_NODES * D + 255) / 256, 256, 0, stream>>>(acc, bns + l * 256, bnw + l * D, bnb + l * D, inb);
    }
    head_k<<<N_NODES, 128, 0, stream>>>(inb, w1, b1, w2, b2, (float*)d_out);
}

// Round 5
// 798.995 us; speedup vs baseline: 2.7092x; 1.0465x over previous
//
#include <hip/hip_runtime.h>

#define N_NODES 50000
#define N_EDGES 800000
#define D 128
#define R_REL 4
#define L_LAYERS 3
#define M_SEG (N_NODES * R_REL)
#define NCOLS 384
#define BN_EPS 1e-5f

typedef unsigned short u16;
typedef __attribute__((ext_vector_type(8))) short short8v;
typedef __attribute__((ext_vector_type(4))) float f32x4;

static __device__ __forceinline__ u16 f2b(float f) {
    union { float f; unsigned int u; } a; a.f = f;
    unsigned int u = a.u;
    return (u16)((u + 0x7FFFu + ((u >> 16) & 1u)) >> 16);
}
static __device__ __forceinline__ float b2f(u16 b) {
    union { unsigned int u; float f; } a; a.u = ((unsigned int)b) << 16;
    return a.f;
}

// ---------------- weight packing: Wpb[(l*5+p)][j=0..383][k=0..127] bf16 (transposed)
__global__ void pack_w(const float* __restrict__ Wsk, const float* __restrict__ Wfsk,
                       const float* __restrict__ Wr, const float* __restrict__ Wf,
                       u16* __restrict__ Wpb) {
    int idx = blockIdx.x * 256 + threadIdx.x;
    if (idx >= L_LAYERS * 5 * NCOLS * D) return;
    int k = idx & 127;
    int rem = idx >> 7;
    int j = rem % NCOLS;
    int lp = rem / NCOLS;
    int l = lp / 5, p = lp % 5;
    float v;
    if (p == 0) {
        v = (j < D) ? Wsk[(l * D + k) * D + j] : Wfsk[(l * D + k) * 2 * D + (j - D)];
    } else {
        int r = p - 1;
        v = (j < D) ? Wr[((l * R_REL + r) * D + k) * D + j]
                    : Wf[((l * R_REL + r) * D + k) * 2 * D + (j - D)];
    }
    Wpb[idx] = f2b(v);
}

__global__ void cvt_bf16(const float* __restrict__ x, u16* __restrict__ xb) {
    int idx = blockIdx.x * 256 + threadIdx.x;
    if (idx >= N_NODES * D) return;
    xb[idx] = f2b(x[idx]);
}

// ---------------- CSR build over segments seg = dst*R + etype (rank captured here)
__global__ void hist_k(const int* __restrict__ dst, const int* __restrict__ et,
                       int* __restrict__ cnt, int* __restrict__ rank) {
    int e = blockIdx.x * 256 + threadIdx.x;
    if (e >= N_EDGES) return;
    rank[e] = atomicAdd(&cnt[dst[e] * R_REL + et[e]], 1);
}

__global__ void scan_a(const int* __restrict__ cnt, int* __restrict__ bsum) {
    __shared__ int sm[256];
    int t = threadIdx.x;
    int idx = blockIdx.x * 256 + t;
    sm[t] = (idx < M_SEG) ? cnt[idx] : 0;
    __syncthreads();
    for (int s = 128; s > 0; s >>= 1) {
        if (t < s) sm[t] += sm[t + s];
        __syncthreads();
    }
    if (t == 0) bsum[blockIdx.x] = sm[0];
}

#define NB_SCAN 782  // ceil(200000/256)
__global__ void scan_b(const int* __restrict__ bsum, int* __restrict__ bsumex, int* __restrict__ offs) {
    __shared__ int sm[1024];
    int t = threadIdx.x;
    int v = (t < NB_SCAN) ? bsum[t] : 0;
    sm[t] = v;
    __syncthreads();
    for (int d = 1; d < 1024; d <<= 1) {
        int add = (t >= d) ? sm[t - d] : 0;
        __syncthreads();
        sm[t] += add;
        __syncthreads();
    }
    if (t < NB_SCAN) bsumex[t] = sm[t] - v;
    if (t == NB_SCAN - 1) offs[M_SEG] = sm[t];
}

__global__ void scan_c(const int* __restrict__ cnt, const int* __restrict__ bsumex, int* __restrict__ offs) {
    __shared__ int sm[256];
    int t = threadIdx.x;
    int idx = blockIdx.x * 256 + t;
    int v = (idx < M_SEG) ? cnt[idx] : 0;
    sm[t] = v;
    __syncthreads();
    for (int d = 1; d < 256; d <<= 1) {
        int add = (t >= d) ? sm[t - d] : 0;
        __syncthreads();
        sm[t] += add;
        __syncthreads();
    }
    if (idx < M_SEG) offs[idx] = bsumex[blockIdx.x] + sm[t] - v;
}

__global__ void scatter_k(const int* __restrict__ src, const int* __restrict__ dst,
                          const int* __restrict__ et, const int* __restrict__ offs,
                          const int* __restrict__ rank, int* __restrict__ esrc) {
    int e = blockIdx.x * 256 + threadIdx.x;
    if (e >= N_EDGES) return;
    int seg = dst[e] * R_REL + et[e];
    esrc[offs[seg] + rank[e]] = src[e];
}

// ============ relation-plane GEMM: bufR[p][N][384] = A @ W(1+p)^T, p=0..3
// grid (391, 4), 512 threads (8 waves 2x4). A-tile staged once; coalesced LDS-transposed epilogue.
__global__ __launch_bounds__(512) void gemm_planes(const uint4* __restrict__ Aq,
                                                   const uint4* __restrict__ Bq,  // layer base [5*384][16]
                                                   u16* __restrict__ bufR) {
    __shared__ uint4 As[128 * 16];
    __shared__ u16 Cs[128 * 128];
    int t = threadIdx.x;
    int m0 = blockIdx.x * 128;
    int p = blockIdx.y;
#pragma unroll
    for (int i = 0; i < 4; ++i) {
        int idx = i * 512 + t;
        int row = idx >> 4, kk = idx & 15;
        int gr = m0 + row;
        if (gr >= N_NODES) gr = N_NODES - 1;
        As[(row << 4) + (kk ^ (row & 7))] = Aq[gr * 16 + kk];
    }
    __syncthreads();
    int lane = t & 63, w = t >> 6;
    int wr = w >> 2, wc = w & 3;
    int lr = lane & 15, lh = lane >> 4;
    short8v a[4][4];
#pragma unroll
    for (int m = 0; m < 4; ++m) {
        int row = wr * 64 + m * 16 + lr;
#pragma unroll
        for (int ks = 0; ks < 4; ++ks)
            a[m][ks] = *reinterpret_cast<const short8v*>(&As[(row << 4) + ((ks * 4 + lh) ^ (row & 7))]);
    }
    const uint4* Bp = Bq + (size_t)(1 + p) * NCOLS * 16;
    u16* Cp = bufR + (size_t)p * N_NODES * NCOLS;
    f32x4 zero = {0.f, 0.f, 0.f, 0.f};
    int srow = t >> 4, sslot = t & 15;   // epilogue read/store coords (32 rows/iter)
#pragma unroll
    for (int chunk = 0; chunk < 3; ++chunk) {
        int n0 = chunk * 128;
        f32x4 acc[4][2];
#pragma unroll
        for (int m = 0; m < 4; ++m)
#pragma unroll
            for (int n = 0; n < 2; ++n) acc[m][n] = zero;
#pragma unroll
        for (int ks = 0; ks < 4; ++ks) {
            short8v b[2];
#pragma unroll
            for (int n = 0; n < 2; ++n) {
                int row = n0 + wc * 32 + n * 16 + lr;
                b[n] = *reinterpret_cast<const short8v*>(&Bp[row * 16 + ks * 4 + lh]);
            }
#pragma unroll
            for (int m = 0; m < 4; ++m)
#pragma unroll
                for (int n = 0; n < 2; ++n)
                    acc[m][n] = __builtin_amdgcn_mfma_f32_16x16x32_bf16(a[m][ks], b[n], acc[m][n], 0, 0, 0);
        }
        __syncthreads();  // previous chunk's Cs reads done
#pragma unroll
        for (int m = 0; m < 4; ++m)
#pragma unroll
            for (int reg = 0; reg < 4; ++reg) {
                int row = wr * 64 + m * 16 + lh * 4 + reg;
#pragma unroll
                for (int n = 0; n < 2; ++n) {
                    int col = wc * 32 + n * 16 + lr;
                    Cs[row * 128 + (col ^ ((lh & 1) << 4))] = f2b(acc[m][n][reg]);
                }
            }
        __syncthreads();
#pragma unroll
        for (int it = 0; it < 4; ++it) {
            int row = it * 32 + srow;
            int gr = m0 + row;
            if (gr < N_NODES) {
                uint4 v = *reinterpret_cast<const uint4*>(
                    &Cs[row * 128 + ((sslot * 8) ^ (((row >> 2) & 1) << 4))]);
                *reinterpret_cast<uint4*>(&Cp[(size_t)gr * NCOLS + n0 + sslot * 8]) = v;
            }
        }
    }
}

// ============ self GEMM fused with FiLM: selfb[N][128] = relu(gamma_s * xsk + beta_s)
__global__ __launch_bounds__(512) void gemm_self(const uint4* __restrict__ Aq,
                                                 const uint4* __restrict__ Bq,  // layer base
                                                 u16* __restrict__ selfb) {
    __shared__ uint4 As[128 * 16];
    __shared__ u16 Cs[128 * 128];
    int t = threadIdx.x;
    int m0 = blockIdx.x * 128;
#pragma unroll
    for (int i = 0; i < 4; ++i) {
        int idx = i * 512 + t;
        int row = idx >> 4, kk = idx & 15;
        int gr = m0 + row;
        if (gr >= N_NODES) gr = N_NODES - 1;
        As[(row << 4) + (kk ^ (row & 7))] = Aq[gr * 16 + kk];
    }
    __syncthreads();
    int lane = t & 63, w = t >> 6;
    int wr = w >> 2, wc = w & 3;
    int lr = lane & 15, lh = lane >> 4;
    short8v a[4][4];
#pragma unroll
    for (int m = 0; m < 4; ++m) {
        int row = wr * 64 + m * 16 + lr;
#pragma unroll
        for (int ks = 0; ks < 4; ++ks)
            a[m][ks] = *reinterpret_cast<const short8v*>(&As[(row << 4) + ((ks * 4 + lh) ^ (row & 7))]);
    }
    f32x4 zero = {0.f, 0.f, 0.f, 0.f};
    f32x4 hx[4][2], hb[4][2];
#pragma unroll
    for (int chunk = 0; chunk < 3; ++chunk) {
        int n0 = chunk * 128;
        f32x4 acc[4][2];
#pragma unroll
        for (int m = 0; m < 4; ++m)
#pragma unroll
            for (int n = 0; n < 2; ++n) acc[m][n] = zero;
#pragma unroll
        for (int ks = 0; ks < 4; ++ks) {
            short8v b[2];
#pragma unroll
            for (int n = 0; n < 2; ++n) {
                int row = n0 + wc * 32 + n * 16 + lr;
                b[n] = *reinterpret_cast<const short8v*>(&Bq[row * 16 + ks * 4 + lh]);
            }
#pragma unroll
            for (int m = 0; m < 4; ++m)
#pragma unroll
                for (int n = 0; n < 2; ++n)
                    acc[m][n] = __builtin_amdgcn_mfma_f32_16x16x32_bf16(a[m][ks], b[n], acc[m][n], 0, 0, 0);
        }
        if (chunk == 0) {
#pragma unroll
            for (int m = 0; m < 4; ++m)
#pragma unroll
                for (int n = 0; n < 2; ++n) hx[m][n] = acc[m][n];
        } else if (chunk == 1) {
#pragma unroll
            for (int m = 0; m < 4; ++m)
#pragma unroll
                for (int n = 0; n < 2; ++n) hb[m][n] = acc[m][n];
        } else {
            // acc = gamma; h = relu(gamma*x + beta)
#pragma unroll
            for (int m = 0; m < 4; ++m)
#pragma unroll
                for (int reg = 0; reg < 4; ++reg) {
                    int row = wr * 64 + m * 16 + lh * 4 + reg;
#pragma unroll
                    for (int n = 0; n < 2; ++n) {
                        int col = wc * 32 + n * 16 + lr;
                        float h = fmaxf(acc[m][n][reg] * hx[m][n][reg] + hb[m][n][reg], 0.f);
                        Cs[row * 128 + (col ^ ((lh & 1) << 4))] = f2b(h);
                    }
                }
        }
    }
    __syncthreads();
    int srow = t >> 4, sslot = t & 15;
#pragma unroll
    for (int it = 0; it < 4; ++it) {
        int row = it * 32 + srow;
        int gr = m0 + row;
        if (gr < N_NODES) {
            uint4 v = *reinterpret_cast<const uint4*>(
                &Cs[row * 128 + ((sslot * 8) ^ (((row >> 2) & 1) << 4))]);
            *reinterpret_cast<uint4*>(&selfb[(size_t)gr * D + sslot * 8]) = v;
        }
    }
}

// ---------------- FUSED per-node agg: wave per node; self preloaded; ushort4; half-wave edges
__global__ __launch_bounds__(256) void film_agg2(const u16* __restrict__ selfb, const u16* __restrict__ bufR,
                                                 const int* __restrict__ offs, const int* __restrict__ esrc,
                                                 float* __restrict__ acc) {
    int t = threadIdx.x;
    int n = blockIdx.x * 4 + (t >> 6);
    int lane = t & 63;
    int cg = (lane & 31) * 4;
    int half = lane >> 5;
    ushort4 hs = *reinterpret_cast<const ushort4*>(&selfb[(size_t)n * D + cg]);
    float h0 = b2f(hs.x), h1 = b2f(hs.y), h2 = b2f(hs.z), h3 = b2f(hs.w);
#pragma unroll
    for (int r = 0; r < R_REL; ++r) {
        const u16* B = bufR + (size_t)r * N_NODES * NCOLS;
        int seg = n * R_REL + r;
        int beg = offs[seg], end = offs[seg + 1];
        if (beg < end) {
            const u16* grow = B + (size_t)n * NCOLS;
            ushort4 b4 = *reinterpret_cast<const ushort4*>(&grow[128 + cg]);
            ushort4 g4 = *reinterpret_cast<const ushort4*>(&grow[256 + cg]);
            float g0 = b2f(g4.x), g1 = b2f(g4.y), g2 = b2f(g4.z), g3 = b2f(g4.w);
            float be0 = b2f(b4.x), be1 = b2f(b4.y), be2 = b2f(b4.z), be3 = b2f(b4.w);
            float s0 = 0.f, s1 = 0.f, s2 = 0.f, s3 = 0.f;
            for (int i = beg + half; i < end; i += 2) {
                int src = esrc[i];
                ushort4 x4 = *reinterpret_cast<const ushort4*>(&B[(size_t)src * NCOLS + cg]);
                s0 += fmaxf(g0 * b2f(x4.x) + be0, 0.f);
                s1 += fmaxf(g1 * b2f(x4.y) + be1, 0.f);
                s2 += fmaxf(g2 * b2f(x4.z) + be2, 0.f);
                s3 += fmaxf(g3 * b2f(x4.w) + be3, 0.f);
            }
            s0 += __shfl_xor(s0, 32);
            s1 += __shfl_xor(s1, 32);
            s2 += __shfl_xor(s2, 32);
            s3 += __shfl_xor(s3, 32);
            float inv = 1.f / (float)(end - beg);
            h0 += s0 * inv; h1 += s1 * inv; h2 += s2 * inv; h3 += s3 * inv;
        }
    }
    if (half == 0) {
        float4 o = make_float4(h0, h1, h2, h3);
        *reinterpret_cast<float4*>(&acc[(size_t)n * D + cg]) = o;
    }
}

// ---------------- batchnorm stats
__global__ __launch_bounds__(256) void bn_stats2(const float* __restrict__ acc, float* __restrict__ sums) {
    __shared__ float sm[256], sm2[256];
    int t = threadIdx.x;
    int c = t & 127, half = t >> 7;
    int rows = (N_NODES + gridDim.x - 1) / gridDim.x;
    int nb = blockIdx.x * rows;
    int n1 = min(nb + rows, N_NODES);
    float s = 0.f, s2 = 0.f;
    for (int n = nb + half; n < n1; n += 2) {
        float v = acc[n * D + c];
        s += v;
        s2 += v * v;
    }
    sm[t] = s; sm2[t] = s2;
    __syncthreads();
    if (t < 128) {
        atomicAdd(&sums[c], sm[t] + sm[t + 128]);
        atomicAdd(&sums[128 + c], sm2[t] + sm2[t + 128]);
    }
}

// ---------------- batchnorm apply -> bf16 next-layer input
__global__ void bn_apply(const float* __restrict__ acc, const float* __restrict__ sums,
                         const float* __restrict__ w, const float* __restrict__ b,
                         u16* __restrict__ hb16) {
    int idx = blockIdx.x * 256 + threadIdx.x;
    if (idx >= N_NODES * D) return;
    int c = idx & 127;
    const float invn = 1.f / (float)N_NODES;
    float mu = sums[c] * invn;
    float var = sums[128 + c] * invn - mu * mu;
    float rs = rsqrtf(var + BN_EPS);
    hb16[idx] = f2b((acc[idx] - mu) * rs * w[c] + b[c]);
}

// ---------------- head
__global__ __launch_bounds__(128) void head_k(const u16* __restrict__ h, const float* __restrict__ w1,
                                              const float* __restrict__ b1, const float* __restrict__ w2,
                                              const float* __restrict__ b2, float* __restrict__ out) {
    __shared__ float hrow[128];
    __shared__ float part[128];
    __shared__ float mid[32];
    int n = blockIdx.x, t = threadIdx.x;
    hrow[t] = b2f(h[n * D + t]);
    __syncthreads();
    int m = t & 31, q = t >> 5;
    float p = 0.f;
#pragma unroll 8
    for (int k = q * 32; k < q * 32 + 32; ++k) p += hrow[k] * w1[k * 32 + m];
    part[t] = p;
    __syncthreads();
    if (t < 32) {
        float v = part[t] + part[t + 32] + part[t + 64] + part[t + 96] + b1[t];
        mid[t] = v > 0.f ? v : 0.2f * v;
    }
    __syncthreads();
    if (t < 40) {
        float o = b2[t];
#pragma unroll 8
        for (int mm = 0; mm < 32; ++mm) o += mid[mm] * w2[mm * 40 + t];
        out[n * 40 + t] = o;
    }
}

extern "C" void kernel_launch(void* const* d_in, const int* in_sizes, int n_in,
                              void* d_out, int out_size, void* d_ws, size_t ws_size,
                              hipStream_t stream) {
    const float* x    = (const float*)d_in[0];
    const int*   ei   = (const int*)d_in[1];
    const int*   et   = (const int*)d_in[2];
    const float* Wsk  = (const float*)d_in[3];
    const float* Wfsk = (const float*)d_in[4];
    const float* Wr   = (const float*)d_in[5];
    const float* Wf   = (const float*)d_in[6];
    const float* bnw  = (const float*)d_in[7];
    const float* bnb  = (const float*)d_in[8];
    const float* w1   = (const float*)d_in[9];
    const float* b1   = (const float*)d_in[10];
    const float* w2   = (const float*)d_in[11];
    const float* b2   = (const float*)d_in[12];
    const int* src = ei;
    const int* dst = ei + N_EDGES;

    char* ws = (char*)d_ws;
    size_t off = 0;
    auto alloc = [&](size_t bytes) -> void* {
        void* p = ws + off;
        off += (bytes + 255) & ~(size_t)255;
        return p;
    };
    u16*   Wpb  = (u16*)alloc((size_t)L_LAYERS * 5 * NCOLS * D * 2);
    u16*   inb  = (u16*)alloc((size_t)N_NODES * D * 2);
    float* acc  = (float*)alloc((size_t)N_NODES * D * 4);
    int*   cnt    = (int*)alloc((size_t)M_SEG * 4);     // contiguous with bns: one memset
    float* bns    = (float*)alloc((size_t)L_LAYERS * 256 * 4);
    int*   offs   = (int*)alloc((size_t)(M_SEG + 1) * 4);
    int*   esrc   = (int*)alloc((size_t)N_EDGES * 4);
    int*   rank   = (int*)alloc((size_t)N_EDGES * 4);
    int*   bsum   = (int*)alloc(1024 * 4);
    int*   bsumex = (int*)alloc(1024 * 4);
    u16*   bufR   = (u16*)alloc((size_t)4 * N_NODES * NCOLS * 2);  // 153.6 MB: 4 planes [N][384]
    u16*   selfb  = (u16*)alloc((size_t)N_NODES * D * 2);          // 12.8 MB

    hipMemsetAsync(cnt, 0, (size_t)M_SEG * 4 + (size_t)L_LAYERS * 1024, stream);

    pack_w<<<(L_LAYERS * 5 * NCOLS * D + 255) / 256, 256, 0, stream>>>(Wsk, Wfsk, Wr, Wf, Wpb);
    cvt_bf16<<<(N_NODES * D + 255) / 256, 256, 0, stream>>>(x, inb);
    hist_k<<<(N_EDGES + 255) / 256, 256, 0, stream>>>(dst, et, cnt, rank);
    scan_a<<<NB_SCAN, 256, 0, stream>>>(cnt, bsum);
    scan_b<<<1, 1024, 0, stream>>>(bsum, bsumex, offs);
    scan_c<<<NB_SCAN, 256, 0, stream>>>(cnt, bsumex, offs);
    scatter_k<<<(N_EDGES + 255) / 256, 256, 0, stream>>>(src, dst, et, offs, rank, esrc);

    const int nbm = (N_NODES + 127) / 128;  // 391
    for (int l = 0; l < L_LAYERS; ++l) {
        const uint4* Aq = (const uint4*)inb;
        const uint4* Wl = (const uint4*)(Wpb + (size_t)(l * 5) * NCOLS * D);
        gemm_planes<<<dim3(nbm, 4), 512, 0, stream>>>(Aq, Wl, bufR);
        gemm_self<<<dim3(nbm, 1), 512, 0, stream>>>(Aq, Wl, selfb);
        film_agg2<<<N_NODES / 4, 256, 0, stream>>>(selfb, bufR, offs, esrc, acc);
        bn_stats2<<<256, 256, 0, stream>>>(acc, bns + l * 256);
        bn_apply<<<(N_NODES * D + 255) / 256, 256, 0, stream>>>(acc, bns + l * 256, bnw + l * D, bnb + l * D, inb);
    }
    head_k<<<N_NODES, 128, 0, stream>>>(inb, w1, b1, w2, b2, (float*)d_out);
}

// Round 7
// 761.290 us; speedup vs baseline: 2.8434x; 1.0495x over previous
//
#include <hip/hip_runtime.h>

#define N_NODES 50000
#define N_EDGES 800000
#define D 128
#define R_REL 4
#define L_LAYERS 3
#define M_SEG (N_NODES * R_REL)
#define NCOLS 384
#define BN_EPS 1e-5f

typedef unsigned short u16;
typedef __attribute__((ext_vector_type(8))) short short8v;
typedef __attribute__((ext_vector_type(4))) float f32x4;

static __device__ __forceinline__ u16 f2b(float f) {
    union { float f; unsigned int u; } a; a.f = f;
    unsigned int u = a.u;
    return (u16)((u + 0x7FFFu + ((u >> 16) & 1u)) >> 16);
}
static __device__ __forceinline__ float b2f(u16 b) {
    union { unsigned int u; float f; } a; a.u = ((unsigned int)b) << 16;
    return a.f;
}

// ---------------- weight packing: Wpb[(l*5+p)][j=0..383][k=0..127] bf16 (transposed)
__global__ void pack_w(const float* __restrict__ Wsk, const float* __restrict__ Wfsk,
                       const float* __restrict__ Wr, const float* __restrict__ Wf,
                       u16* __restrict__ Wpb) {
    int idx = blockIdx.x * 256 + threadIdx.x;
    if (idx >= L_LAYERS * 5 * NCOLS * D) return;
    int k = idx & 127;
    int rem = idx >> 7;
    int j = rem % NCOLS;
    int lp = rem / NCOLS;
    int l = lp / 5, p = lp % 5;
    float v;
    if (p == 0) {
        v = (j < D) ? Wsk[(l * D + k) * D + j] : Wfsk[(l * D + k) * 2 * D + (j - D)];
    } else {
        int r = p - 1;
        v = (j < D) ? Wr[((l * R_REL + r) * D + k) * D + j]
                    : Wf[((l * R_REL + r) * D + k) * 2 * D + (j - D)];
    }
    Wpb[idx] = f2b(v);
}

__global__ void cvt_bf16(const float* __restrict__ x, u16* __restrict__ xb) {
    int idx = blockIdx.x * 256 + threadIdx.x;
    if (idx >= N_NODES * D) return;
    xb[idx] = f2b(x[idx]);
}

// ---------------- CSR build over segments seg = dst*R + etype (rank captured here)
__global__ void hist_k(const int* __restrict__ dst, const int* __restrict__ et,
                       int* __restrict__ cnt, int* __restrict__ rank) {
    int e = blockIdx.x * 256 + threadIdx.x;
    if (e >= N_EDGES) return;
    rank[e] = atomicAdd(&cnt[dst[e] * R_REL + et[e]], 1);
}

__global__ void scan_a(const int* __restrict__ cnt, int* __restrict__ bsum) {
    __shared__ int sm[256];
    int t = threadIdx.x;
    int idx = blockIdx.x * 256 + t;
    sm[t] = (idx < M_SEG) ? cnt[idx] : 0;
    __syncthreads();
    for (int s = 128; s > 0; s >>= 1) {
        if (t < s) sm[t] += sm[t + s];
        __syncthreads();
    }
    if (t == 0) bsum[blockIdx.x] = sm[0];
}

#define NB_SCAN 782  // ceil(200000/256)
__global__ void scan_b(const int* __restrict__ bsum, int* __restrict__ bsumex, int* __restrict__ offs) {
    __shared__ int sm[1024];
    int t = threadIdx.x;
    int v = (t < NB_SCAN) ? bsum[t] : 0;
    sm[t] = v;
    __syncthreads();
    for (int d = 1; d < 1024; d <<= 1) {
        int add = (t >= d) ? sm[t - d] : 0;
        __syncthreads();
        sm[t] += add;
        __syncthreads();
    }
    if (t < NB_SCAN) bsumex[t] = sm[t] - v;
    if (t == NB_SCAN - 1) offs[M_SEG] = sm[t];
}

__global__ void scan_c(const int* __restrict__ cnt, const int* __restrict__ bsumex, int* __restrict__ offs) {
    __shared__ int sm[256];
    int t = threadIdx.x;
    int idx = blockIdx.x * 256 + t;
    int v = (idx < M_SEG) ? cnt[idx] : 0;
    sm[t] = v;
    __syncthreads();
    for (int d = 1; d < 256; d <<= 1) {
        int add = (t >= d) ? sm[t - d] : 0;
        __syncthreads();
        sm[t] += add;
        __syncthreads();
    }
    if (idx < M_SEG) offs[idx] = bsumex[blockIdx.x] + sm[t] - v;
}

__global__ void scatter_k(const int* __restrict__ src, const int* __restrict__ dst,
                          const int* __restrict__ et, const int* __restrict__ offs,
                          const int* __restrict__ rank, int* __restrict__ esrc) {
    int e = blockIdx.x * 256 + threadIdx.x;
    if (e >= N_EDGES) return;
    int seg = dst[e] * R_REL + et[e];
    esrc[offs[seg] + rank[e]] = src[e];
}

// ============ unified per-layer GEMM, grid (391, 5):
// p<4: relation planes -> xrp[p][N][128] (xr) and gbp[N][p][256] (beta|gamma)
// p==4: self FiLM fused -> selfb[N][128] = relu(gamma_s * xsk + beta_s)
__global__ __launch_bounds__(512) void gemm_all(const uint4* __restrict__ Aq,
                                                const uint4* __restrict__ Bq,   // layer base [5*384][16]
                                                u16* __restrict__ xrp, u16* __restrict__ gbp,
                                                u16* __restrict__ selfb) {
    __shared__ uint4 As[128 * 16];
    __shared__ u16 Cs[128 * 128];
    int t = threadIdx.x;
    int m0 = blockIdx.x * 128;
    int p = blockIdx.y;
#pragma unroll
    for (int i = 0; i < 4; ++i) {
        int idx = i * 512 + t;
        int row = idx >> 4, kk = idx & 15;
        int gr = m0 + row;
        if (gr >= N_NODES) gr = N_NODES - 1;
        As[(row << 4) + (kk ^ (row & 7))] = Aq[gr * 16 + kk];
    }
    __syncthreads();
    int lane = t & 63, w = t >> 6;
    int wr = w >> 2, wc = w & 3;
    int lr = lane & 15, lh = lane >> 4;
    short8v a[4][4];
#pragma unroll
    for (int m = 0; m < 4; ++m) {
        int row = wr * 64 + m * 16 + lr;
#pragma unroll
        for (int ks = 0; ks < 4; ++ks)
            a[m][ks] = *reinterpret_cast<const short8v*>(&As[(row << 4) + ((ks * 4 + lh) ^ (row & 7))]);
    }
    const uint4* Bp = Bq + (size_t)((p < 4) ? (1 + p) : 0) * NCOLS * 16;
    f32x4 zero = {0.f, 0.f, 0.f, 0.f};
    f32x4 hx[4][2], hb[4][2];
    int srow = t >> 4, sslot = t & 15;
#pragma unroll
    for (int chunk = 0; chunk < 3; ++chunk) {
        int n0 = chunk * 128;
        f32x4 acc[4][2];
#pragma unroll
        for (int m = 0; m < 4; ++m)
#pragma unroll
            for (int n = 0; n < 2; ++n) acc[m][n] = zero;
#pragma unroll
        for (int ks = 0; ks < 4; ++ks) {
            short8v b[2];
#pragma unroll
            for (int n = 0; n < 2; ++n) {
                int row = n0 + wc * 32 + n * 16 + lr;
                b[n] = *reinterpret_cast<const short8v*>(&Bp[row * 16 + ks * 4 + lh]);
            }
#pragma unroll
            for (int m = 0; m < 4; ++m)
#pragma unroll
                for (int n = 0; n < 2; ++n)
                    acc[m][n] = __builtin_amdgcn_mfma_f32_16x16x32_bf16(a[m][ks], b[n], acc[m][n], 0, 0, 0);
        }
        if (p < 4) {
            __syncthreads();  // previous chunk's Cs reads done
#pragma unroll
            for (int m = 0; m < 4; ++m)
#pragma unroll
                for (int reg = 0; reg < 4; ++reg) {
                    int row = wr * 64 + m * 16 + lh * 4 + reg;
#pragma unroll
                    for (int n = 0; n < 2; ++n) {
                        int col = wc * 32 + n * 16 + lr;
                        Cs[row * 128 + (col ^ ((lh & 1) << 4))] = f2b(acc[m][n][reg]);
                    }
                }
            __syncthreads();
#pragma unroll
            for (int it = 0; it < 4; ++it) {
                int row = it * 32 + srow;
                int gr = m0 + row;
                if (gr < N_NODES) {
                    uint4 v = *reinterpret_cast<const uint4*>(
                        &Cs[row * 128 + ((sslot * 8) ^ (((row >> 2) & 1) << 4))]);
                    if (chunk == 0)
                        *reinterpret_cast<uint4*>(&xrp[((size_t)p * N_NODES + gr) * 128 + sslot * 8]) = v;
                    else if (chunk == 1)
                        *reinterpret_cast<uint4*>(&gbp[(size_t)gr * 1024 + p * 256 + sslot * 8]) = v;
                    else
                        *reinterpret_cast<uint4*>(&gbp[(size_t)gr * 1024 + p * 256 + 128 + sslot * 8]) = v;
                }
            }
        } else {
            if (chunk == 0) {
#pragma unroll
                for (int m = 0; m < 4; ++m)
#pragma unroll
                    for (int n = 0; n < 2; ++n) hx[m][n] = acc[m][n];
            } else if (chunk == 1) {
#pragma unroll
                for (int m = 0; m < 4; ++m)
#pragma unroll
                    for (int n = 0; n < 2; ++n) hb[m][n] = acc[m][n];
            } else {
#pragma unroll
                for (int m = 0; m < 4; ++m)
#pragma unroll
                    for (int reg = 0; reg < 4; ++reg) {
                        int row = wr * 64 + m * 16 + lh * 4 + reg;
#pragma unroll
                        for (int n = 0; n < 2; ++n) {
                            int col = wc * 32 + n * 16 + lr;
                            float h = fmaxf(acc[m][n][reg] * hx[m][n][reg] + hb[m][n][reg], 0.f);
                            Cs[row * 128 + (col ^ ((lh & 1) << 4))] = f2b(h);
                        }
                    }
            }
        }
    }
    if (p == 4) {
        __syncthreads();
#pragma unroll
        for (int it = 0; it < 4; ++it) {
            int row = it * 32 + srow;
            int gr = m0 + row;
            if (gr < N_NODES) {
                uint4 v = *reinterpret_cast<const uint4*>(
                    &Cs[row * 128 + ((sslot * 8) ^ (((row >> 2) & 1) << 4))]);
                *reinterpret_cast<uint4*>(&selfb[(size_t)gr * D + sslot * 8]) = v;
            }
        }
    }
}

// ---------------- agg: wave/node; quarter-wave per relation; uint4 gathers; 4 streams in flight
__global__ __launch_bounds__(256) void film_agg3(const u16* __restrict__ selfb, const u16* __restrict__ xrp,
                                                 const u16* __restrict__ gbp,
                                                 const int* __restrict__ offs, const int* __restrict__ esrc,
                                                 float* __restrict__ acc) {
    int t = threadIdx.x;
    int n = blockIdx.x * 4 + (t >> 6);
    int lane = t & 63;
    int cq = lane & 15;        // col quad: cols cq*8 .. cq*8+7
    int rel = lane >> 4;       // quarter-wave owns one relation
    float h[8];
#pragma unroll
    for (int j = 0; j < 8; ++j) h[j] = 0.f;
    int seg = n * R_REL + rel;
    int beg = offs[seg], end = offs[seg + 1];
    if (beg < end) {
        uint4 bv = *reinterpret_cast<const uint4*>(&gbp[(size_t)n * 1024 + rel * 256 + cq * 8]);
        uint4 gv = *reinterpret_cast<const uint4*>(&gbp[(size_t)n * 1024 + rel * 256 + 128 + cq * 8]);
        const u16* bp = (const u16*)&bv;
        const u16* gp = (const u16*)&gv;
        float be[8], ga[8];
#pragma unroll
        for (int j = 0; j < 8; ++j) { be[j] = b2f(bp[j]); ga[j] = b2f(gp[j]); }
        const u16* X = xrp + (size_t)rel * N_NODES * D;
        float s[8];
#pragma unroll
        for (int j = 0; j < 8; ++j) s[j] = 0.f;
        for (int i = beg; i < end; ++i) {
            int src = esrc[i];
            uint4 xv = *reinterpret_cast<const uint4*>(&X[(size_t)src * D + cq * 8]);
            const u16* xp = (const u16*)&xv;
#pragma unroll
            for (int j = 0; j < 8; ++j) s[j] += fmaxf(ga[j] * b2f(xp[j]) + be[j], 0.f);
        }
        float inv = 1.f / (float)(end - beg);
#pragma unroll
        for (int j = 0; j < 8; ++j) h[j] = s[j] * inv;
    }
    // combine the 4 relation quarters, then add self
#pragma unroll
    for (int j = 0; j < 8; ++j) {
        h[j] += __shfl_xor(h[j], 16);
        h[j] += __shfl_xor(h[j], 32);
    }
    uint4 sv = *reinterpret_cast<const uint4*>(&selfb[(size_t)n * D + cq * 8]);
    const u16* sp = (const u16*)&sv;
#pragma unroll
    for (int j = 0; j < 8; ++j) h[j] += b2f(sp[j]);
    if (lane < 16) {
        float4 o0 = make_float4(h[0], h[1], h[2], h[3]);
        float4 o1 = make_float4(h[4], h[5], h[6], h[7]);
        *reinterpret_cast<float4*>(&acc[(size_t)n * D + cq * 8]) = o0;
        *reinterpret_cast<float4*>(&acc[(size_t)n * D + cq * 8 + 4]) = o1;
    }
}

// ---------------- batchnorm stats
__global__ __launch_bounds__(256) void bn_stats2(const float* __restrict__ acc, float* __restrict__ sums) {
    __shared__ float sm[256], sm2[256];
    int t = threadIdx.x;
    int c = t & 127, half = t >> 7;
    int rows = (N_NODES + gridDim.x - 1) / gridDim.x;
    int nb = blockIdx.x * rows;
    int n1 = min(nb + rows, N_NODES);
    float s = 0.f, s2 = 0.f;
    for (int n = nb + half; n < n1; n += 2) {
        float v = acc[n * D + c];
        s += v;
        s2 += v * v;
    }
    sm[t] = s; sm2[t] = s2;
    __syncthreads();
    if (t < 128) {
        atomicAdd(&sums[c], sm[t] + sm[t + 128]);
        atomicAdd(&sums[128 + c], sm2[t] + sm2[t + 128]);
    }
}

// ---------------- batchnorm apply -> bf16 next-layer input
__global__ void bn_apply(const float* __restrict__ acc, const float* __restrict__ sums,
                         const float* __restrict__ w, const float* __restrict__ b,
                         u16* __restrict__ hb16) {
    int idx = blockIdx.x * 256 + threadIdx.x;
    if (idx >= N_NODES * D) return;
    int c = idx & 127;
    const float invn = 1.f / (float)N_NODES;
    float mu = sums[c] * invn;
    float var = sums[128 + c] * invn - mu * mu;
    float rs = rsqrtf(var + BN_EPS);
    hb16[idx] = f2b((acc[idx] - mu) * rs * w[c] + b[c]);
}

// ---------------- head
__global__ __launch_bounds__(128) void head_k(const u16* __restrict__ h, const float* __restrict__ w1,
                                              const float* __restrict__ b1, const float* __restrict__ w2,
                                              const float* __restrict__ b2, float* __restrict__ out) {
    __shared__ float hrow[128];
    __shared__ float part[128];
    __shared__ float mid[32];
    int n = blockIdx.x, t = threadIdx.x;
    hrow[t] = b2f(h[n * D + t]);
    __syncthreads();
    int m = t & 31, q = t >> 5;
    float p = 0.f;
#pragma unroll 8
    for (int k = q * 32; k < q * 32 + 32; ++k) p += hrow[k] * w1[k * 32 + m];
    part[t] = p;
    __syncthreads();
    if (t < 32) {
        float v = part[t] + part[t + 32] + part[t + 64] + part[t + 96] + b1[t];
        mid[t] = v > 0.f ? v : 0.2f * v;
    }
    __syncthreads();
    if (t < 40) {
        float o = b2[t];
#pragma unroll 8
        for (int mm = 0; mm < 32; ++mm) o += mid[mm] * w2[mm * 40 + t];
        out[n * 40 + t] = o;
    }
}

extern "C" void kernel_launch(void* const* d_in, const int* in_sizes, int n_in,
                              void* d_out, int out_size, void* d_ws, size_t ws_size,
                              hipStream_t stream) {
    const float* x    = (const float*)d_in[0];
    const int*   ei   = (const int*)d_in[1];
    const int*   et   = (const int*)d_in[2];
    const float* Wsk  = (const float*)d_in[3];
    const float* Wfsk = (const float*)d_in[4];
    const float* Wr   = (const float*)d_in[5];
    const float* Wf   = (const float*)d_in[6];
    const float* bnw  = (const float*)d_in[7];
    const float* bnb  = (const float*)d_in[8];
    const float* w1   = (const float*)d_in[9];
    const float* b1   = (const float*)d_in[10];
    const float* w2   = (const float*)d_in[11];
    const float* b2   = (const float*)d_in[12];
    const int* src = ei;
    const int* dst = ei + N_EDGES;

    char* ws = (char*)d_ws;
    size_t off = 0;
    auto alloc = [&](size_t bytes) -> void* {
        void* p = ws + off;
        off += (bytes + 255) & ~(size_t)255;
        return p;
    };
    u16*   Wpb  = (u16*)alloc((size_t)L_LAYERS * 5 * NCOLS * D * 2);
    u16*   inb  = (u16*)alloc((size_t)N_NODES * D * 2);
    float* acc  = (float*)alloc((size_t)N_NODES * D * 4);
    int*   cnt    = (int*)alloc((size_t)M_SEG * 4);     // contiguous with bns: one memset
    float* bns    = (float*)alloc((size_t)L_LAYERS * 256 * 4);
    int*   offs   = (int*)alloc((size_t)(M_SEG + 1) * 4);
    int*   esrc   = (int*)alloc((size_t)N_EDGES * 4);
    int*   rank   = (int*)alloc((size_t)N_EDGES * 4);
    int*   bsum   = (int*)alloc(1024 * 4);
    int*   bsumex = (int*)alloc(1024 * 4);
    u16*   xrp    = (u16*)alloc((size_t)R_REL * N_NODES * D * 2);   // 51.2 MB compact gather planes
    u16*   gbp    = (u16*)alloc((size_t)N_NODES * R_REL * 256 * 2); // 102.4 MB node-major beta|gamma
    u16*   selfb  = (u16*)alloc((size_t)N_NODES * D * 2);           // 12.8 MB

    hipMemsetAsync(cnt, 0, (size_t)M_SEG * 4 + (size_t)L_LAYERS * 1024, stream);

    pack_w<<<(L_LAYERS * 5 * NCOLS * D + 255) / 256, 256, 0, stream>>>(Wsk, Wfsk, Wr, Wf, Wpb);
    cvt_bf16<<<(N_NODES * D + 255) / 256, 256, 0, stream>>>(x, inb);
    hist_k<<<(N_EDGES + 255) / 256, 256, 0, stream>>>(dst, et, cnt, rank);
    scan_a<<<NB_SCAN, 256, 0, stream>>>(cnt, bsum);
    scan_b<<<1, 1024, 0, stream>>>(bsum, bsumex, offs);
    scan_c<<<NB_SCAN, 256, 0, stream>>>(cnt, bsumex, offs);
    scatter_k<<<(N_EDGES + 255) / 256, 256, 0, stream>>>(src, dst, et, offs, rank, esrc);

    const int nbm = (N_NODES + 127) / 128;  // 391
    for (int l = 0; l < L_LAYERS; ++l) {
        gemm_all<<<dim3(nbm, 5), 512, 0, stream>>>((const uint4*)inb,
                                                   (const uint4*)(Wpb + (size_t)(l * 5) * NCOLS * D),
                                                   xrp, gbp, selfb);
        film_agg3<<<N_NODES / 4, 256, 0, stream>>>(selfb, xrp, gbp, offs, esrc, acc);
        bn_stats2<<<256, 256, 0, stream>>>(acc, bns + l * 256);
        bn_apply<<<(N_NODES * D + 255) / 256, 256, 0, stream>>>(acc, bns + l * 256, bnw + l * D, bnb + l * D, inb);
    }
    head_k<<<N_NODES, 128, 0, stream>>>(inb, w1, b1, w2, b2, (float*)d_out);
}